// Round 18
// baseline (332.951 us; speedup 1.0000x reference)
//
#include <hip/hip_runtime.h>

#define DIMC 384
#define NHEADS 12
#define NTOK 144
#define TABLEN 529
#define BWIN 512
#define NWIN 16
#define CPBH 512
#define LOG2E 1.4426950408889634f

typedef unsigned short u16;
typedef unsigned int u32;
typedef __attribute__((ext_vector_type(8))) short short8;
typedef __attribute__((ext_vector_type(4))) float f32x4;

#define MFMA(a, b, c) __builtin_amdgcn_mfma_f32_16x16x32_bf16((a), (b), (c), 0, 0, 0)

__device__ __forceinline__ u16 f2bf(float f) {
  union { float f; u32 u; } v; v.f = f;
  u32 r = v.u + 0x7fffu + ((v.u >> 16) & 1u);
  return (u16)(r >> 16);
}
__device__ __forceinline__ u32 pk2(float a, float b) {
  return (u32)f2bf(a) | ((u32)f2bf(b) << 16);
}
__device__ __forceinline__ u32 cvtpk(float lo, float hi) {
  u32 r;
  asm("v_cvt_pk_bf16_f32 %0, %1, %2" : "=v"(r) : "v"(lo), "v"(hi));
  return r;
}

// ---------------- f32 -> bf16 bulk convert ----------------
__global__ __launch_bounds__(256) void cvt_bf16(const float* __restrict__ in,
                                                u16* __restrict__ out, int n8) {
  int i = blockIdx.x * 256 + threadIdx.x;
  if (i >= n8) return;
  const float4* p = (const float4*)(in + (size_t)i * 8);
  float4 a = p[0], b = p[1];
  uint4 r;
  r.x = pk2(a.x, a.y); r.y = pk2(a.z, a.w);
  r.z = pk2(b.x, b.y); r.w = pk2(b.z, b.w);
  *(uint4*)(out + (size_t)i * 8) = r;
}

// ---------------- CPB-MLP table: one block per table entry i (529 blocks, R17-proven) ----------------
__global__ __launch_bounds__(256) void cpb_kernel(const float* __restrict__ rct,
                                                  const float* __restrict__ w1,
                                                  const float* __restrict__ b1,
                                                  const float* __restrict__ w2,
                                                  const float* __restrict__ logit_scale,
                                                  float* __restrict__ bias_tab,
                                                  float* __restrict__ scalev) {
  __shared__ float h1[CPBH];
  int i = blockIdx.x;
  int tid = threadIdx.x;
  if (i == 0 && tid < NHEADS)
    scalev[tid] = __expf(fminf(logit_scale[tid], 4.60517018598809f));
  float c0 = rct[2 * i], c1 = rct[2 * i + 1];
  for (int k = tid; k < CPBH; k += 256)
    h1[k] = fmaxf(0.f, fmaf(c0, w1[2 * k], fmaf(c1, w1[2 * k + 1], b1[k])));
  __syncthreads();
  int wv = tid >> 6, lane = tid & 63;
#pragma unroll
  for (int hh = 0; hh < 3; ++hh) {
    int h = wv * 3 + hh;
    const float* w2h = w2 + (size_t)h * CPBH;
    float acc = 0.f;
#pragma unroll
    for (int k = 0; k < CPBH; k += 64) acc = fmaf(h1[k + lane], w2h[k + lane], acc);
    acc += __shfl_xor(acc, 1); acc += __shfl_xor(acc, 2); acc += __shfl_xor(acc, 4);
    acc += __shfl_xor(acc, 8); acc += __shfl_xor(acc, 16); acc += __shfl_xor(acc, 32);
    if (lane == 0) bias_tab[i * NHEADS + h] = 16.f / (1.f + __expf(-acc));
  }
}

// ---------------- combined bias: cb = (rpb + mask) * log2(e), fp32, x4 vectorized ----------------
// R18: pre-scaled by LOG2E so attn softmax uses exp2 directly (exact identity).
__global__ __launch_bounds__(256) void cbias_kernel(const int* __restrict__ rpi,
                                                    const float* __restrict__ bias_tab,
                                                    const float* __restrict__ mask,
                                                    float* __restrict__ cb) {
  int e4 = blockIdx.x * 256 + threadIdx.x;
  if (e4 >= NWIN * NHEADS * NTOK * NTOK / 4) return;
  int m0 = (e4 * 4) % NTOK;
  int t = (e4 * 4) / NTOK;
  int n = t % NTOK; t /= NTOK;
  int h = t % NHEADS;
  int w = t / NHEADS;
  int4 idx = *(const int4*)(rpi + n * NTOK + m0);
  float4 mk = *(const float4*)(mask + ((size_t)(w * NTOK + n)) * NTOK + m0);
  float4 r;
  r.x = (bias_tab[idx.x * NHEADS + h] + mk.x) * LOG2E;
  r.y = (bias_tab[idx.y * NHEADS + h] + mk.y) * LOG2E;
  r.z = (bias_tab[idx.z * NHEADS + h] + mk.z) * LOG2E;
  r.w = (bias_tab[idx.w * NHEADS + h] + mk.w) * LOG2E;
  *(float4*)(cb + (size_t)e4 * 4) = r;
}

// ---------------- fused QKV-projection + cosine attention per (window b, head-PAIR hp) ----------------
// 576 threads = 9 waves; wave wv owns query rows [16wv, 16wv+16).
// R18 deltas vs R17 (both exact-math identities):
//  - log2e folded into siq (q scale) + cb -> softmax uses exp2f (v_exp_f32, no mul)
//  - 1/sum DEFERRED to epilogue (rv[r] scales po), P stored unnormalized in [0,1]
__global__ __launch_bounds__(576) void attn_fused(
    const u16* __restrict__ xb, const u16* __restrict__ wb,
    const float* __restrict__ q_bias, const float* __restrict__ k_bias,
    const float* __restrict__ v_bias, const float* __restrict__ cb,
    const float* __restrict__ scalev, u16* __restrict__ ctx) {
  __shared__ u16 smem[22656];  // 45312 B -> 3 blocks/CU (wave-capped anyway)
  u16* qn = smem;               // [144][40] (per-head phases 2+)
  u16* kn = smem + 5760;        // [144][40]
  u16* vT = smem + 11520;       // [32][168]
  u16* Pc = smem + 16896;       // [144][40] (phase 5, wave-private rows)
  u16* xs = smem;               // phase 1: [144][64] half-buffered x rows (18432 B)
  u16* wsm = smem + 9216;       // phase 1: [192][64] half-buffered W rows, 2 heads (24576 B)

  // w-grouped XCD decode: XCD x owns mask-windows {2x,2x+1}; cb set = 2.4MB < 4MB L2
  int bid = blockIdx.x;
  int xcd = bid & 7;
  int i = bid >> 3;          // 0..383
  int wsub = i / 192;        // 0..1
  int j = i - wsub * 192;    // 0..191
  int bI = j / 6;            // 0..31
  int hp = j - bI * 6;       // 0..5 head pair
  int w = xcd * 2 + wsub;
  int b = bI * NWIN + w;
  int h0 = hp * 2;

  int tid = threadIdx.x;
  int lane = tid & 63, wv = tid >> 6;   // wv 0..8
  int g = lane >> 4, c = lane & 15;
  int rbase = wv * 16;

  // ---- phase 1: QKV for BOTH heads, K chunked by 32, prefetch depth 2 ----
  f32x4 acc[2][6];
#pragma unroll
  for (int hh = 0; hh < 2; ++hh)
#pragma unroll
    for (int d = 0; d < 6; ++d) acc[hh][d] = (f32x4){0.f, 0.f, 0.f, 0.f};

  int r4 = tid >> 2, b4 = tid & 3;   // x/W0 row r4, 16B content chunk b4
  bool hasW1 = tid < 192;            // W rows 144..191 on threads 0..191
  int wr1 = 144 + r4;
  int wg0 = (r4 >> 6) * DIMC + (h0 + ((r4 >> 5) & 1)) * 32 + (r4 & 31);
  int wg1 = (wr1 >> 6) * DIMC + (h0 + ((wr1 >> 5) & 1)) * 32 + (wr1 & 31);
  const u16* xg = xb + ((size_t)b * NTOK + r4) * DIMC + b4 * 8;
  const u16* wgp0 = wb + (size_t)wg0 * DIMC + b4 * 8;
  const u16* wgp1 = wb + (size_t)wg1 * DIMC + b4 * 8;
  // half-buffer slots: content chunk (b4 + 4*parity), slot = chunk ^ (row&7)
  int xo0 = r4 * 64 + 8 * (b4 ^ (r4 & 7));
  int xo1 = r4 * 64 + 8 * ((b4 + 4) ^ (r4 & 7));
  int w1o0 = wr1 * 64 + 8 * (b4 ^ (wr1 & 7));
  int w1o1 = wr1 * 64 + 8 * ((b4 + 4) ^ (wr1 & 7));

  // named depth-2 buffers (A = even tiles, B = odd tiles)
  uint4 pxA, pw0A, pw1A, pxB, pw0B, pw1B;
  pxA = *(const uint4*)(xg);
  pw0A = *(const uint4*)(wgp0);
  if (hasW1) pw1A = *(const uint4*)(wgp1);
  pxB = *(const uint4*)(xg + 32);
  pw0B = *(const uint4*)(wgp0 + 32);
  if (hasW1) pw1B = *(const uint4*)(wgp1 + 32);

#pragma unroll
  for (int tt = 0; tt < 6; ++tt) {
    // ---- even sub-iter: tile t=2tt (half 0) ----
    *(uint4*)(xs + xo0) = pxA;
    *(uint4*)(wsm + xo0) = pw0A;
    if (hasW1) *(uint4*)(wsm + w1o0) = pw1A;
    __syncthreads();
    if (tt < 5) {  // issue loads for tile 2tt+2 (2 iterations of cover)
      int k0 = (2 * tt + 2) * 32;
      pxA = *(const uint4*)(xg + k0);
      pw0A = *(const uint4*)(wgp0 + k0);
      if (hasW1) pw1A = *(const uint4*)(wgp1 + k0);
    }
    {
      int arow = rbase + c;
      short8 ax = *(const short8*)(xs + arow * 64 + 8 * (g ^ (arow & 7)));
#pragma unroll
      for (int hh = 0; hh < 2; ++hh)
#pragma unroll
        for (int d = 0; d < 6; ++d) {
          int row = (d >> 1) * 64 + hh * 32 + (d & 1) * 16 + c;
          short8 bw = *(const short8*)(wsm + row * 64 + 8 * (g ^ (row & 7)));
          acc[hh][d] = MFMA(ax, bw, acc[hh][d]);
        }
    }
    // ---- odd sub-iter: tile t=2tt+1 (half 1) ----
    *(uint4*)(xs + xo1) = pxB;
    *(uint4*)(wsm + xo1) = pw0B;
    if (hasW1) *(uint4*)(wsm + w1o1) = pw1B;
    __syncthreads();
    if (tt < 5) {  // issue loads for tile 2tt+3
      int k0 = (2 * tt + 3) * 32;
      pxB = *(const uint4*)(xg + k0);
      pw0B = *(const uint4*)(wgp0 + k0);
      if (hasW1) pw1B = *(const uint4*)(wgp1 + k0);
    }
    {
      int arow = rbase + c;
      short8 ax = *(const short8*)(xs + arow * 64 + 8 * ((g + 4) ^ (arow & 7)));
#pragma unroll
      for (int hh = 0; hh < 2; ++hh)
#pragma unroll
        for (int d = 0; d < 6; ++d) {
          int row = (d >> 1) * 64 + hh * 32 + (d & 1) * 16 + c;
          short8 bw = *(const short8*)(wsm + row * 64 + 8 * ((g + 4) ^ (row & 7)));
          acc[hh][d] = MFMA(ax, bw, acc[hh][d]);
        }
    }
    // no trailing barrier: next sub-iter writes the other half
  }
  __syncthreads();  // phase-1 reads done; smem may be repurposed

  // ---- phases 2-5 per head (sequential, shared buffers) ----
#pragma unroll
  for (int hh = 0; hh < 2; ++hh) {
    int h = h0 + hh;
    if (hh) __syncthreads();  // head B waits for head A's LDS reads

    // phase 2: bias + cosine-normalize in-register, write qn/kn (f2bf) + vT (packed)
    float sch = scalev[h] * LOG2E;  // exp2 folding: logits pre-scaled by log2(e)
    float qb0 = q_bias[h * 32 + c], qb1 = q_bias[h * 32 + 16 + c];
    float kb0 = k_bias[h * 32 + c], kb1 = k_bias[h * 32 + 16 + c];
    float vb0 = v_bias[h * 32 + c], vb1 = v_bias[h * 32 + 16 + c];
    float v0a[4], v1a[4];
#pragma unroll
    for (int r = 0; r < 4; ++r) {
      int row = rbase + g * 4 + r;
      float q0 = acc[hh][0][r] + qb0, q1 = acc[hh][1][r] + qb1;
      float ssq = q0 * q0 + q1 * q1;
      ssq += __shfl_xor(ssq, 1); ssq += __shfl_xor(ssq, 2);
      ssq += __shfl_xor(ssq, 4); ssq += __shfl_xor(ssq, 8);
      float siq = sch / sqrtf(ssq);
      qn[row * 40 + c] = f2bf(q0 * siq);
      qn[row * 40 + 16 + c] = f2bf(q1 * siq);
      float k0v = acc[hh][2][r] + kb0, k1v = acc[hh][3][r] + kb1;
      float ssk = k0v * k0v + k1v * k1v;
      ssk += __shfl_xor(ssk, 1); ssk += __shfl_xor(ssk, 2);
      ssk += __shfl_xor(ssk, 4); ssk += __shfl_xor(ssk, 8);
      float sik = 1.f / sqrtf(ssk);
      kn[row * 40 + c] = f2bf(k0v * sik);
      kn[row * 40 + 16 + c] = f2bf(k1v * sik);
      v0a[r] = acc[hh][4][r] + vb0;
      v1a[r] = acc[hh][5][r] + vb1;
    }
    {  // packed vT writes
      int m0 = rbase + g * 4;
      u16* p0 = vT + c * 168 + m0;
      u16* p1 = vT + (16 + c) * 168 + m0;
      *(u32*)p0 = cvtpk(v0a[0], v0a[1]);
      *(u32*)(p0 + 2) = cvtpk(v0a[2], v0a[3]);
      *(u32*)p1 = cvtpk(v1a[0], v1a[1]);
      *(u32*)(p1 + 2) = cvtpk(v1a[2], v1a[3]);
    }
    if (hh == 0 && tid < 32) {  // zero vT m-pad (144..167) once
      uint4 z4 = {0u, 0u, 0u, 0u};
      *(uint4*)(vT + tid * 168 + 144) = z4;
      *(uint4*)(vT + tid * 168 + 152) = z4;
      *(uint4*)(vT + tid * 168 + 160) = z4;
    }
    __syncthreads();

    // phase 3: S = qn . kn^T  (logits already x log2e via siq)
    short8 aq = *(const short8*)(qn + (rbase + c) * 40 + g * 8);
    f32x4 S[9];
#pragma unroll
    for (int mt = 0; mt < 9; ++mt) {
      short8 bk = *(const short8*)(kn + (mt * 16 + c) * 40 + g * 8);
      f32x4 z = (f32x4){0.f, 0.f, 0.f, 0.f};
      S[mt] = MFMA(aq, bk, z);
    }

    // phase 4: + cb (pre-scaled), row softmax via exp2; 1/sum kept in rv[] (deferred)
    const float* cbh = cb + (((size_t)w * NHEADS + h) * NTOK) * NTOK;
    float rv[4];
#pragma unroll
    for (int r = 0; r < 4; ++r) {
      int row = rbase + g * 4 + r;
      const float* crow = cbh + (size_t)row * NTOK + c;
      float sv[9];
      float mx = -1e30f;
#pragma unroll
      for (int mt = 0; mt < 9; ++mt) {
        float s = S[mt][r] + crow[mt * 16];
        sv[mt] = s;
        mx = fmaxf(mx, s);
      }
      mx = fmaxf(mx, __shfl_xor(mx, 1)); mx = fmaxf(mx, __shfl_xor(mx, 2));
      mx = fmaxf(mx, __shfl_xor(mx, 4)); mx = fmaxf(mx, __shfl_xor(mx, 8));
      float sum = 0.f;
#pragma unroll
      for (int mt = 0; mt < 9; ++mt) {
        float p = exp2f(sv[mt] - mx);   // = exp(logit - max), exact identity
        sv[mt] = p;
        sum += p;
      }
      sum += __shfl_xor(sum, 1); sum += __shfl_xor(sum, 2);
      sum += __shfl_xor(sum, 4); sum += __shfl_xor(sum, 8);
      rv[r] = 1.f / sum;
#pragma unroll
      for (int mt = 0; mt < 9; ++mt) S[mt][r] = sv[mt];  // unnormalized P in [0,1]
    }

    // phase 5: PV via per-wave P bounce (wave-private Pc rows, no barriers)
    f32x4 po[2];
    po[0] = (f32x4){0.f, 0.f, 0.f, 0.f};
    po[1] = (f32x4){0.f, 0.f, 0.f, 0.f};
    for (int ck = 0; ck < 5; ++ck) {
#pragma unroll
      for (int mt2 = 0; mt2 < 2; ++mt2) {
        int MT = ck * 2 + mt2;
#pragma unroll
        for (int r = 0; r < 4; ++r) {
          int row = rbase + g * 4 + r;
          float p = (MT < 9) ? S[MT][r] : 0.f;
          Pc[row * 40 + mt2 * 16 + c] = f2bf(p);
        }
      }
      short8 pa = *(const short8*)(Pc + (rbase + c) * 40 + g * 8);
#pragma unroll
      for (int dt = 0; dt < 2; ++dt) {
        short8 vb = *(const short8*)(vT + (dt * 16 + c) * 168 + ck * 32 + g * 8);
        po[dt] = MFMA(pa, vb, po[dt]);
      }
    }

    // epilogue: normalize by rv[r] here (deferred 1/sum), write ctx bf16
#pragma unroll
    for (int dt = 0; dt < 2; ++dt)
#pragma unroll
      for (int r = 0; r < 4; ++r) {
        int n = rbase + g * 4 + r;
        ctx[((size_t)b * NTOK + n) * DIMC + h * 32 + dt * 16 + c] = f2bf(po[dt][r] * rv[r]);
      }
  }
}

// ---------------- output projection: (73728 x 384) @ (384 x 384)^T + bias, bf16 MFMA ----------------
__global__ __launch_bounds__(256) void proj_gemm(const u16* __restrict__ ctx,
                                                 const u16* __restrict__ pwb,
                                                 const float* __restrict__ proj_b,
                                                 float* __restrict__ out) {
  __shared__ u16 As[128 * 64];
  __shared__ u16 Bs[128 * 64];
  int bid = blockIdx.x;
  int nblk = bid % 3, mblk = bid / 3;
  size_t gm0 = (size_t)mblk * 128;
  int gn0 = nblk * 128;
  int tid = threadIdx.x, lane = tid & 63, wid = tid >> 6;
  int wr = wid >> 1, wc = wid & 1, g = lane >> 4, c = lane & 15;
  f32x4 acc[4][4];
#pragma unroll
  for (int i = 0; i < 4; ++i)
#pragma unroll
    for (int j = 0; j < 4; ++j) acc[i][j] = (f32x4){0.f, 0.f, 0.f, 0.f};

  for (int t = 0; t < 6; ++t) {
    int k0 = t * 64;
#pragma unroll
    for (int p = 0; p < 4; ++p) {
      int row = p * 32 + (tid >> 3);
      int seg = (tid & 7) * 8;
      uint4 va = *(const uint4*)(ctx + (gm0 + row) * DIMC + k0 + seg);
      *(uint4*)(As + row * 64 + seg) = va;
      uint4 vb = *(const uint4*)(pwb + (size_t)(gn0 + row) * DIMC + k0 + seg);
      *(uint4*)(Bs + row * 64 + seg) = vb;
    }
    __syncthreads();
#pragma unroll
    for (int kk = 0; kk < 64; kk += 32) {
      short8 a[4], bfr[4];
#pragma unroll
      for (int mi = 0; mi < 4; ++mi)
        a[mi] = *(const short8*)(As + (wr * 64 + mi * 16 + c) * 64 + kk + g * 8);
#pragma unroll
      for (int ni = 0; ni < 4; ++ni)
        bfr[ni] = *(const short8*)(Bs + (wc * 64 + ni * 16 + c) * 64 + kk + g * 8);
#pragma unroll
      for (int mi = 0; mi < 4; ++mi)
#pragma unroll
        for (int ni = 0; ni < 4; ++ni)
          acc[mi][ni] = MFMA(a[mi], bfr[ni], acc[mi][ni]);
    }
    __syncthreads();
  }
#pragma unroll
  for (int mi = 0; mi < 4; ++mi)
#pragma unroll
    for (int ni = 0; ni < 4; ++ni) {
      int gcol = gn0 + wc * 64 + ni * 16 + c;
      float bv = proj_b[gcol];
#pragma unroll
      for (int r = 0; r < 4; ++r) {
        size_t grow = gm0 + wr * 64 + mi * 16 + g * 4 + r;
        out[grow * DIMC + gcol] = acc[mi][ni][r] + bv;
      }
    }
}

extern "C" void kernel_launch(void* const* d_in, const int* in_sizes, int n_in,
                              void* d_out, int out_size, void* d_ws, size_t ws_size,
                              hipStream_t stream) {
  const float* x = (const float*)d_in[0];
  const float* rct = (const float*)d_in[1];
  const int* rpi = (const int*)d_in[2];
  const float* mask = (const float*)d_in[3];
  const float* qkv_w = (const float*)d_in[4];
  const float* q_bias = (const float*)d_in[5];
  const float* k_bias = (const float*)d_in[6];
  const float* v_bias = (const float*)d_in[7];
  const float* logit_scale = (const float*)d_in[8];
  const float* cpb_w1 = (const float*)d_in[9];
  const float* cpb_b1 = (const float*)d_in[10];
  const float* cpb_w2 = (const float*)d_in[11];
  const float* proj_w = (const float*)d_in[12];
  const float* proj_b = (const float*)d_in[13];
  float* out = (float*)d_out;

  char* ws = (char*)d_ws;
  size_t off = 0;
  auto alloc = [&](size_t bytes) {
    void* p = ws + off;
    off = (off + bytes + 255) & ~(size_t)255;
    return p;
  };
  const size_t NX = (size_t)BWIN * NTOK * DIMC;  // 28311552
  u16* xb = (u16*)alloc(NX * 2);
  u16* wqb = (u16*)alloc((size_t)3 * DIMC * DIMC * 2);
  u16* pwb = (u16*)alloc((size_t)DIMC * DIMC * 2);
  u16* ctx = (u16*)alloc(NX * 2);
  float* cbv = (float*)alloc((size_t)NWIN * NHEADS * NTOK * NTOK * 4);
  float* bias_tab = (float*)alloc((size_t)TABLEN * NHEADS * 4);
  float* scalev = (float*)alloc(64 * 4);

  cvt_bf16<<<(int)(NX / 8 + 255) / 256, 256, 0, stream>>>(x, xb, (int)(NX / 8));
  cvt_bf16<<<(3 * DIMC * DIMC / 8 + 255) / 256, 256, 0, stream>>>(qkv_w, wqb, 3 * DIMC * DIMC / 8);
  cvt_bf16<<<(DIMC * DIMC / 8 + 255) / 256, 256, 0, stream>>>(proj_w, pwb, DIMC * DIMC / 8);
  cpb_kernel<<<TABLEN, 256, 0, stream>>>(
      rct, cpb_w1, cpb_b1, cpb_w2, logit_scale, bias_tab, scalev);
  cbias_kernel<<<(NWIN * NHEADS * NTOK * NTOK / 4 + 255) / 256, 256, 0, stream>>>(
      rpi, bias_tab, mask, cbv);
  attn_fused<<<BWIN * 6, 576, 0, stream>>>(
      xb, wqb, q_bias, k_bias, v_bias, cbv, scalev, ctx);
  proj_gemm<<<(BWIN * NTOK / 128) * 3, 256, 0, stream>>>(ctx, pwb, proj_b, out);
}

// Round 19
// 328.504 us; speedup vs baseline: 1.0135x; 1.0135x over previous
//
#include <hip/hip_runtime.h>

#define DIMC 384
#define NHEADS 12
#define NTOK 144
#define TABLEN 529
#define BWIN 512
#define NWIN 16
#define CPBH 512

typedef unsigned short u16;
typedef unsigned int u32;
typedef __attribute__((ext_vector_type(8))) short short8;
typedef __attribute__((ext_vector_type(4))) float f32x4;

#define MFMA(a, b, c) __builtin_amdgcn_mfma_f32_16x16x32_bf16((a), (b), (c), 0, 0, 0)

__device__ __forceinline__ u16 f2bf(float f) {
  union { float f; u32 u; } v; v.f = f;
  u32 r = v.u + 0x7fffu + ((v.u >> 16) & 1u);
  return (u16)(r >> 16);
}
__device__ __forceinline__ u32 pk2(float a, float b) {
  return (u32)f2bf(a) | ((u32)f2bf(b) << 16);
}
__device__ __forceinline__ u32 cvtpk(float lo, float hi) {
  u32 r;
  asm("v_cvt_pk_bf16_f32 %0, %1, %2" : "=v"(r) : "v"(lo), "v"(hi));
  return r;
}

// ---------------- f32 -> bf16 bulk convert (weights only) ----------------
__global__ __launch_bounds__(256) void cvt_bf16(const float* __restrict__ in,
                                                u16* __restrict__ out, int n8) {
  int i = blockIdx.x * 256 + threadIdx.x;
  if (i >= n8) return;
  const float4* p = (const float4*)(in + (size_t)i * 8);
  float4 a = p[0], b = p[1];
  uint4 r;
  r.x = pk2(a.x, a.y); r.y = pk2(a.z, a.w);
  r.z = pk2(b.x, b.y); r.w = pk2(b.z, b.w);
  *(uint4*)(out + (size_t)i * 8) = r;
}

// ---------------- CPB-MLP table: one block per table entry i (529 blocks, R17-proven) ----------------
__global__ __launch_bounds__(256) void cpb_kernel(const float* __restrict__ rct,
                                                  const float* __restrict__ w1,
                                                  const float* __restrict__ b1,
                                                  const float* __restrict__ w2,
                                                  const float* __restrict__ logit_scale,
                                                  float* __restrict__ bias_tab,
                                                  float* __restrict__ scalev) {
  __shared__ float h1[CPBH];
  int i = blockIdx.x;
  int tid = threadIdx.x;
  if (i == 0 && tid < NHEADS)
    scalev[tid] = __expf(fminf(logit_scale[tid], 4.60517018598809f));
  float c0 = rct[2 * i], c1 = rct[2 * i + 1];
  for (int k = tid; k < CPBH; k += 256)
    h1[k] = fmaxf(0.f, fmaf(c0, w1[2 * k], fmaf(c1, w1[2 * k + 1], b1[k])));
  __syncthreads();
  int wv = tid >> 6, lane = tid & 63;
#pragma unroll
  for (int hh = 0; hh < 3; ++hh) {
    int h = wv * 3 + hh;
    const float* w2h = w2 + (size_t)h * CPBH;
    float acc = 0.f;
#pragma unroll
    for (int k = 0; k < CPBH; k += 64) acc = fmaf(h1[k + lane], w2h[k + lane], acc);
    acc += __shfl_xor(acc, 1); acc += __shfl_xor(acc, 2); acc += __shfl_xor(acc, 4);
    acc += __shfl_xor(acc, 8); acc += __shfl_xor(acc, 16); acc += __shfl_xor(acc, 32);
    if (lane == 0) bias_tab[i * NHEADS + h] = 16.f / (1.f + __expf(-acc));
  }
}

// ---------------- combined bias: cb[w][h][n][m] = rpb + mask (fp32, x4 vectorized) ----------------
__global__ __launch_bounds__(256) void cbias_kernel(const int* __restrict__ rpi,
                                                    const float* __restrict__ bias_tab,
                                                    const float* __restrict__ mask,
                                                    float* __restrict__ cb) {
  int e4 = blockIdx.x * 256 + threadIdx.x;
  if (e4 >= NWIN * NHEADS * NTOK * NTOK / 4) return;
  int m0 = (e4 * 4) % NTOK;
  int t = (e4 * 4) / NTOK;
  int n = t % NTOK; t /= NTOK;
  int h = t % NHEADS;
  int w = t / NHEADS;
  int4 idx = *(const int4*)(rpi + n * NTOK + m0);
  float4 mk = *(const float4*)(mask + ((size_t)(w * NTOK + n)) * NTOK + m0);
  float4 r;
  r.x = bias_tab[idx.x * NHEADS + h] + mk.x;
  r.y = bias_tab[idx.y * NHEADS + h] + mk.y;
  r.z = bias_tab[idx.z * NHEADS + h] + mk.z;
  r.w = bias_tab[idx.w * NHEADS + h] + mk.w;
  *(float4*)(cb + (size_t)e4 * 4) = r;
}

// ---------------- fused QKV-projection + cosine attention per (window b, head-PAIR hp) ----------------
// 576 threads = 9 waves; wave wv owns query rows [16wv, 16wv+16).
// R19: phases 2-5 reverted to R17-proven form (R18's exp2+deferred-sum regressed +10us).
// NEW: x read as f32 directly with cvt fused into staging (deletes the 170MB x-convert
// pass). Staging is depth-2-prefetched and non-critical (R15); the 6 head-pair blocks
// per window are XCD-colocated (w-grouped decode) so f32 re-reads are L2-served.
__global__ __launch_bounds__(576) void attn_fused(
    const float* __restrict__ xf, const u16* __restrict__ wb,
    const float* __restrict__ q_bias, const float* __restrict__ k_bias,
    const float* __restrict__ v_bias, const float* __restrict__ cb,
    const float* __restrict__ scalev, u16* __restrict__ ctx) {
  __shared__ u16 smem[22656];  // 45312 B
  u16* qn = smem;               // [144][40] (per-head phases 2+)
  u16* kn = smem + 5760;        // [144][40]
  u16* vT = smem + 11520;       // [32][168]
  u16* Pc = smem + 16896;       // [144][40] (phase 5, wave-private rows)
  u16* xs = smem;               // phase 1: [144][64] half-buffered x rows (18432 B)
  u16* wsm = smem + 9216;       // phase 1: [192][64] half-buffered W rows, 2 heads (24576 B)

  // w-grouped XCD decode: XCD x owns mask-windows {2x,2x+1}; cb set = 2.4MB < 4MB L2
  int bid = blockIdx.x;
  int xcd = bid & 7;
  int i = bid >> 3;          // 0..383
  int wsub = i / 192;        // 0..1
  int j = i - wsub * 192;    // 0..191
  int bI = j / 6;            // 0..31
  int hp = j - bI * 6;       // 0..5 head pair
  int w = xcd * 2 + wsub;
  int b = bI * NWIN + w;
  int h0 = hp * 2;

  int tid = threadIdx.x;
  int lane = tid & 63, wv = tid >> 6;   // wv 0..8
  int g = lane >> 4, c = lane & 15;
  int rbase = wv * 16;

  // ---- phase 1: QKV for BOTH heads, K chunked by 32, prefetch depth 2, fused x-cvt ----
  f32x4 acc[2][6];
#pragma unroll
  for (int hh = 0; hh < 2; ++hh)
#pragma unroll
    for (int d = 0; d < 6; ++d) acc[hh][d] = (f32x4){0.f, 0.f, 0.f, 0.f};

  int r4 = tid >> 2, b4 = tid & 3;   // x/W0 row r4, 16B content chunk b4
  bool hasW1 = tid < 192;            // W rows 144..191 on threads 0..191
  int wr1 = 144 + r4;
  int wg0 = (r4 >> 6) * DIMC + (h0 + ((r4 >> 5) & 1)) * 32 + (r4 & 31);
  int wg1 = (wr1 >> 6) * DIMC + (h0 + ((wr1 >> 5) & 1)) * 32 + (wr1 & 31);
  const float* xg = xf + ((size_t)b * NTOK + r4) * DIMC + b4 * 8;
  const u16* wgp0 = wb + (size_t)wg0 * DIMC + b4 * 8;
  const u16* wgp1 = wb + (size_t)wg1 * DIMC + b4 * 8;
  // half-buffer slots: content chunk (b4 + 4*parity), slot = chunk ^ (row&7)
  int xo0 = r4 * 64 + 8 * (b4 ^ (r4 & 7));
  int xo1 = r4 * 64 + 8 * ((b4 + 4) ^ (r4 & 7));
  int w1o0 = wr1 * 64 + 8 * (b4 ^ (wr1 & 7));
  int w1o1 = wr1 * 64 + 8 * ((b4 + 4) ^ (wr1 & 7));

  // named depth-2 buffers (A = even tiles, B = odd tiles); x in f32
  float4 pxAa, pxAb, pxBa, pxBb;
  uint4 pw0A, pw1A, pw0B, pw1B;
  pxAa = *(const float4*)(xg);
  pxAb = *(const float4*)(xg + 4);
  pw0A = *(const uint4*)(wgp0);
  if (hasW1) pw1A = *(const uint4*)(wgp1);
  pxBa = *(const float4*)(xg + 32);
  pxBb = *(const float4*)(xg + 36);
  pw0B = *(const uint4*)(wgp0 + 32);
  if (hasW1) pw1B = *(const uint4*)(wgp1 + 32);

#pragma unroll
  for (int tt = 0; tt < 6; ++tt) {
    // ---- even sub-iter: tile t=2tt (half 0) ----
    {
      uint4 v;
      v.x = cvtpk(pxAa.x, pxAa.y); v.y = cvtpk(pxAa.z, pxAa.w);
      v.z = cvtpk(pxAb.x, pxAb.y); v.w = cvtpk(pxAb.z, pxAb.w);
      *(uint4*)(xs + xo0) = v;
    }
    *(uint4*)(wsm + xo0) = pw0A;
    if (hasW1) *(uint4*)(wsm + w1o0) = pw1A;
    __syncthreads();
    if (tt < 5) {  // issue loads for tile 2tt+2 (2 iterations of cover)
      int k0 = (2 * tt + 2) * 32;
      pxAa = *(const float4*)(xg + k0);
      pxAb = *(const float4*)(xg + k0 + 4);
      pw0A = *(const uint4*)(wgp0 + k0);
      if (hasW1) pw1A = *(const uint4*)(wgp1 + k0);
    }
    {
      int arow = rbase + c;
      short8 ax = *(const short8*)(xs + arow * 64 + 8 * (g ^ (arow & 7)));
#pragma unroll
      for (int hh = 0; hh < 2; ++hh)
#pragma unroll
        for (int d = 0; d < 6; ++d) {
          int row = (d >> 1) * 64 + hh * 32 + (d & 1) * 16 + c;
          short8 bw = *(const short8*)(wsm + row * 64 + 8 * (g ^ (row & 7)));
          acc[hh][d] = MFMA(ax, bw, acc[hh][d]);
        }
    }
    // ---- odd sub-iter: tile t=2tt+1 (half 1) ----
    {
      uint4 v;
      v.x = cvtpk(pxBa.x, pxBa.y); v.y = cvtpk(pxBa.z, pxBa.w);
      v.z = cvtpk(pxBb.x, pxBb.y); v.w = cvtpk(pxBb.z, pxBb.w);
      *(uint4*)(xs + xo1) = v;
    }
    *(uint4*)(wsm + xo1) = pw0B;
    if (hasW1) *(uint4*)(wsm + w1o1) = pw1B;
    __syncthreads();
    if (tt < 5) {  // issue loads for tile 2tt+3
      int k0 = (2 * tt + 3) * 32;
      pxBa = *(const float4*)(xg + k0);
      pxBb = *(const float4*)(xg + k0 + 4);
      pw0B = *(const uint4*)(wgp0 + k0);
      if (hasW1) pw1B = *(const uint4*)(wgp1 + k0);
    }
    {
      int arow = rbase + c;
      short8 ax = *(const short8*)(xs + arow * 64 + 8 * ((g + 4) ^ (arow & 7)));
#pragma unroll
      for (int hh = 0; hh < 2; ++hh)
#pragma unroll
        for (int d = 0; d < 6; ++d) {
          int row = (d >> 1) * 64 + hh * 32 + (d & 1) * 16 + c;
          short8 bw = *(const short8*)(wsm + row * 64 + 8 * ((g + 4) ^ (row & 7)));
          acc[hh][d] = MFMA(ax, bw, acc[hh][d]);
        }
    }
    // no trailing barrier: next sub-iter writes the other half
  }
  __syncthreads();  // phase-1 reads done; smem may be repurposed

  // ---- phases 2-5 per head (sequential, shared buffers; R17-proven form) ----
#pragma unroll
  for (int hh = 0; hh < 2; ++hh) {
    int h = h0 + hh;
    if (hh) __syncthreads();  // head B waits for head A's LDS reads

    // phase 2: bias + cosine-normalize in-register, write qn/kn (f2bf) + vT (packed)
    float sch = scalev[h];
    float qb0 = q_bias[h * 32 + c], qb1 = q_bias[h * 32 + 16 + c];
    float kb0 = k_bias[h * 32 + c], kb1 = k_bias[h * 32 + 16 + c];
    float vb0 = v_bias[h * 32 + c], vb1 = v_bias[h * 32 + 16 + c];
    float v0a[4], v1a[4];
#pragma unroll
    for (int r = 0; r < 4; ++r) {
      int row = rbase + g * 4 + r;
      float q0 = acc[hh][0][r] + qb0, q1 = acc[hh][1][r] + qb1;
      float ssq = q0 * q0 + q1 * q1;
      ssq += __shfl_xor(ssq, 1); ssq += __shfl_xor(ssq, 2);
      ssq += __shfl_xor(ssq, 4); ssq += __shfl_xor(ssq, 8);
      float siq = sch / sqrtf(ssq);
      qn[row * 40 + c] = f2bf(q0 * siq);
      qn[row * 40 + 16 + c] = f2bf(q1 * siq);
      float k0v = acc[hh][2][r] + kb0, k1v = acc[hh][3][r] + kb1;
      float ssk = k0v * k0v + k1v * k1v;
      ssk += __shfl_xor(ssk, 1); ssk += __shfl_xor(ssk, 2);
      ssk += __shfl_xor(ssk, 4); ssk += __shfl_xor(ssk, 8);
      float sik = 1.f / sqrtf(ssk);
      kn[row * 40 + c] = f2bf(k0v * sik);
      kn[row * 40 + 16 + c] = f2bf(k1v * sik);
      v0a[r] = acc[hh][4][r] + vb0;
      v1a[r] = acc[hh][5][r] + vb1;
    }
    {  // packed vT writes
      int m0 = rbase + g * 4;
      u16* p0 = vT + c * 168 + m0;
      u16* p1 = vT + (16 + c) * 168 + m0;
      *(u32*)p0 = cvtpk(v0a[0], v0a[1]);
      *(u32*)(p0 + 2) = cvtpk(v0a[2], v0a[3]);
      *(u32*)p1 = cvtpk(v1a[0], v1a[1]);
      *(u32*)(p1 + 2) = cvtpk(v1a[2], v1a[3]);
    }
    if (hh == 0 && tid < 32) {  // zero vT m-pad (144..167) once
      uint4 z4 = {0u, 0u, 0u, 0u};
      *(uint4*)(vT + tid * 168 + 144) = z4;
      *(uint4*)(vT + tid * 168 + 152) = z4;
      *(uint4*)(vT + tid * 168 + 160) = z4;
    }
    __syncthreads();

    // phase 3: S = qn . kn^T
    short8 aq = *(const short8*)(qn + (rbase + c) * 40 + g * 8);
    f32x4 S[9];
#pragma unroll
    for (int mt = 0; mt < 9; ++mt) {
      short8 bk = *(const short8*)(kn + (mt * 16 + c) * 40 + g * 8);
      f32x4 z = (f32x4){0.f, 0.f, 0.f, 0.f};
      S[mt] = MFMA(aq, bk, z);
    }

    // phase 4: + (rpb + mask), row softmax (folded 1/sum into P)
    const float* cbh = cb + (((size_t)w * NHEADS + h) * NTOK) * NTOK;
#pragma unroll
    for (int r = 0; r < 4; ++r) {
      int row = rbase + g * 4 + r;
      const float* crow = cbh + (size_t)row * NTOK + c;
      float sv[9];
      float mx = -1e30f;
#pragma unroll
      for (int mt = 0; mt < 9; ++mt) {
        float s = S[mt][r] + crow[mt * 16];
        sv[mt] = s;
        mx = fmaxf(mx, s);
      }
      mx = fmaxf(mx, __shfl_xor(mx, 1)); mx = fmaxf(mx, __shfl_xor(mx, 2));
      mx = fmaxf(mx, __shfl_xor(mx, 4)); mx = fmaxf(mx, __shfl_xor(mx, 8));
      float sum = 0.f;
#pragma unroll
      for (int mt = 0; mt < 9; ++mt) {
        float p = __expf(sv[mt] - mx);
        sv[mt] = p;
        sum += p;
      }
      sum += __shfl_xor(sum, 1); sum += __shfl_xor(sum, 2);
      sum += __shfl_xor(sum, 4); sum += __shfl_xor(sum, 8);
      float rinv = 1.f / sum;
#pragma unroll
      for (int mt = 0; mt < 9; ++mt) S[mt][r] = sv[mt] * rinv;
    }

    // phase 5: PV via per-wave P bounce (wave-private Pc rows, no barriers)
    f32x4 po[2];
    po[0] = (f32x4){0.f, 0.f, 0.f, 0.f};
    po[1] = (f32x4){0.f, 0.f, 0.f, 0.f};
    for (int ck = 0; ck < 5; ++ck) {
#pragma unroll
      for (int mt2 = 0; mt2 < 2; ++mt2) {
        int MT = ck * 2 + mt2;
#pragma unroll
        for (int r = 0; r < 4; ++r) {
          int row = rbase + g * 4 + r;
          float p = (MT < 9) ? S[MT][r] : 0.f;
          Pc[row * 40 + mt2 * 16 + c] = f2bf(p);
        }
      }
      short8 pa = *(const short8*)(Pc + (rbase + c) * 40 + g * 8);
#pragma unroll
      for (int dt = 0; dt < 2; ++dt) {
        short8 vb = *(const short8*)(vT + (dt * 16 + c) * 168 + ck * 32 + g * 8);
        po[dt] = MFMA(pa, vb, po[dt]);
      }
    }

    // epilogue: ctx[b*144+n][h*32+d] bf16 (R17-proven scalar form)
#pragma unroll
    for (int dt = 0; dt < 2; ++dt)
#pragma unroll
      for (int r = 0; r < 4; ++r) {
        int n = rbase + g * 4 + r;
        ctx[((size_t)b * NTOK + n) * DIMC + h * 32 + dt * 16 + c] = f2bf(po[dt][r]);
      }
  }
}

// ---------------- output projection: (73728 x 384) @ (384 x 384)^T + bias, bf16 MFMA ----------------
__global__ __launch_bounds__(256) void proj_gemm(const u16* __restrict__ ctx,
                                                 const u16* __restrict__ pwb,
                                                 const float* __restrict__ proj_b,
                                                 float* __restrict__ out) {
  __shared__ u16 As[128 * 64];
  __shared__ u16 Bs[128 * 64];
  int bid = blockIdx.x;
  int nblk = bid % 3, mblk = bid / 3;
  size_t gm0 = (size_t)mblk * 128;
  int gn0 = nblk * 128;
  int tid = threadIdx.x, lane = tid & 63, wid = tid >> 6;
  int wr = wid >> 1, wc = wid & 1, g = lane >> 4, c = lane & 15;
  f32x4 acc[4][4];
#pragma unroll
  for (int i = 0; i < 4; ++i)
#pragma unroll
    for (int j = 0; j < 4; ++j) acc[i][j] = (f32x4){0.f, 0.f, 0.f, 0.f};

  for (int t = 0; t < 6; ++t) {
    int k0 = t * 64;
#pragma unroll
    for (int p = 0; p < 4; ++p) {
      int row = p * 32 + (tid >> 3);
      int seg = (tid & 7) * 8;
      uint4 va = *(const uint4*)(ctx + (gm0 + row) * DIMC + k0 + seg);
      *(uint4*)(As + row * 64 + seg) = va;
      uint4 vb = *(const uint4*)(pwb + (size_t)(gn0 + row) * DIMC + k0 + seg);
      *(uint4*)(Bs + row * 64 + seg) = vb;
    }
    __syncthreads();
#pragma unroll
    for (int kk = 0; kk < 64; kk += 32) {
      short8 a[4], bfr[4];
#pragma unroll
      for (int mi = 0; mi < 4; ++mi)
        a[mi] = *(const short8*)(As + (wr * 64 + mi * 16 + c) * 64 + kk + g * 8);
#pragma unroll
      for (int ni = 0; ni < 4; ++ni)
        bfr[ni] = *(const short8*)(Bs + (wc * 64 + ni * 16 + c) * 64 + kk + g * 8);
#pragma unroll
      for (int mi = 0; mi < 4; ++mi)
#pragma unroll
        for (int ni = 0; ni < 4; ++ni)
          acc[mi][ni] = MFMA(a[mi], bfr[ni], acc[mi][ni]);
    }
    __syncthreads();
  }
#pragma unroll
  for (int mi = 0; mi < 4; ++mi)
#pragma unroll
    for (int ni = 0; ni < 4; ++ni) {
      int gcol = gn0 + wc * 64 + ni * 16 + c;
      float bv = proj_b[gcol];
#pragma unroll
      for (int r = 0; r < 4; ++r) {
        size_t grow = gm0 + wr * 64 + mi * 16 + g * 4 + r;
        out[grow * DIMC + gcol] = acc[mi][ni][r] + bv;
      }
    }
}

extern "C" void kernel_launch(void* const* d_in, const int* in_sizes, int n_in,
                              void* d_out, int out_size, void* d_ws, size_t ws_size,
                              hipStream_t stream) {
  const float* x = (const float*)d_in[0];
  const float* rct = (const float*)d_in[1];
  const int* rpi = (const int*)d_in[2];
  const float* mask = (const float*)d_in[3];
  const float* qkv_w = (const float*)d_in[4];
  const float* q_bias = (const float*)d_in[5];
  const float* k_bias = (const float*)d_in[6];
  const float* v_bias = (const float*)d_in[7];
  const float* logit_scale = (const float*)d_in[8];
  const float* cpb_w1 = (const float*)d_in[9];
  const float* cpb_b1 = (const float*)d_in[10];
  const float* cpb_w2 = (const float*)d_in[11];
  const float* proj_w = (const float*)d_in[12];
  const float* proj_b = (const float*)d_in[13];
  float* out = (float*)d_out;

  char* ws = (char*)d_ws;
  size_t off = 0;
  auto alloc = [&](size_t bytes) {
    void* p = ws + off;
    off = (off + bytes + 255) & ~(size_t)255;
    return p;
  };
  const size_t NX = (size_t)BWIN * NTOK * DIMC;  // 28311552
  u16* wqb = (u16*)alloc((size_t)3 * DIMC * DIMC * 2);
  u16* pwb = (u16*)alloc((size_t)DIMC * DIMC * 2);
  u16* ctx = (u16*)alloc(NX * 2);
  float* cbv = (float*)alloc((size_t)NWIN * NHEADS * NTOK * NTOK * 4);
  float* bias_tab = (float*)alloc((size_t)TABLEN * NHEADS * 4);
  float* scalev = (float*)alloc(64 * 4);

  cvt_bf16<<<(3 * DIMC * DIMC / 8 + 255) / 256, 256, 0, stream>>>(qkv_w, wqb, 3 * DIMC * DIMC / 8);
  cvt_bf16<<<(DIMC * DIMC / 8 + 255) / 256, 256, 0, stream>>>(proj_w, pwb, DIMC * DIMC / 8);
  cpb_kernel<<<TABLEN, 256, 0, stream>>>(
      rct, cpb_w1, cpb_b1, cpb_w2, logit_scale, bias_tab, scalev);
  cbias_kernel<<<(NWIN * NHEADS * NTOK * NTOK / 4 + 255) / 256, 256, 0, stream>>>(
      rpi, bias_tab, mask, cbv);
  attn_fused<<<BWIN * 6, 576, 0, stream>>>(
      x, wqb, q_bias, k_bias, v_bias, cbv, scalev, ctx);
  proj_gemm<<<(BWIN * NTOK / 128) * 3, 256, 0, stream>>>(ctx, pwb, proj_b, out);
}

// Round 20
// 324.357 us; speedup vs baseline: 1.0265x; 1.0128x over previous
//
#include <hip/hip_runtime.h>

#define DIMC 384
#define NHEADS 12
#define NTOK 144
#define TABLEN 529
#define BWIN 512
#define NWIN 16
#define CPBH 512

typedef unsigned short u16;
typedef unsigned int u32;
typedef __attribute__((ext_vector_type(8))) short short8;
typedef __attribute__((ext_vector_type(4))) float f32x4;

#define MFMA(a, b, c) __builtin_amdgcn_mfma_f32_16x16x32_bf16((a), (b), (c), 0, 0, 0)

__device__ __forceinline__ u16 f2bf(float f) {
  union { float f; u32 u; } v; v.f = f;
  u32 r = v.u + 0x7fffu + ((v.u >> 16) & 1u);
  return (u16)(r >> 16);
}
__device__ __forceinline__ u32 pk2(float a, float b) {
  return (u32)f2bf(a) | ((u32)f2bf(b) << 16);
}
__device__ __forceinline__ u32 cvtpk(float lo, float hi) {
  u32 r;
  asm("v_cvt_pk_bf16_f32 %0, %1, %2" : "=v"(r) : "v"(lo), "v"(hi));
  return r;
}

// ---------------- f32 -> bf16 bulk convert ----------------
__global__ __launch_bounds__(256) void cvt_bf16(const float* __restrict__ in,
                                                u16* __restrict__ out, int n8) {
  int i = blockIdx.x * 256 + threadIdx.x;
  if (i >= n8) return;
  const float4* p = (const float4*)(in + (size_t)i * 8);
  float4 a = p[0], b = p[1];
  uint4 r;
  r.x = pk2(a.x, a.y); r.y = pk2(a.z, a.w);
  r.z = pk2(b.x, b.y); r.w = pk2(b.z, b.w);
  *(uint4*)(out + (size_t)i * 8) = r;
}

// ---------------- CPB-MLP table: one block per table entry i (529 blocks, R17-proven) ----------------
__global__ __launch_bounds__(256) void cpb_kernel(const float* __restrict__ rct,
                                                  const float* __restrict__ w1,
                                                  const float* __restrict__ b1,
                                                  const float* __restrict__ w2,
                                                  const float* __restrict__ logit_scale,
                                                  float* __restrict__ bias_tab,
                                                  float* __restrict__ scalev) {
  __shared__ float h1[CPBH];
  int i = blockIdx.x;
  int tid = threadIdx.x;
  if (i == 0 && tid < NHEADS)
    scalev[tid] = __expf(fminf(logit_scale[tid], 4.60517018598809f));
  float c0 = rct[2 * i], c1 = rct[2 * i + 1];
  for (int k = tid; k < CPBH; k += 256)
    h1[k] = fmaxf(0.f, fmaf(c0, w1[2 * k], fmaf(c1, w1[2 * k + 1], b1[k])));
  __syncthreads();
  int wv = tid >> 6, lane = tid & 63;
#pragma unroll
  for (int hh = 0; hh < 3; ++hh) {
    int h = wv * 3 + hh;
    const float* w2h = w2 + (size_t)h * CPBH;
    float acc = 0.f;
#pragma unroll
    for (int k = 0; k < CPBH; k += 64) acc = fmaf(h1[k + lane], w2h[k + lane], acc);
    acc += __shfl_xor(acc, 1); acc += __shfl_xor(acc, 2); acc += __shfl_xor(acc, 4);
    acc += __shfl_xor(acc, 8); acc += __shfl_xor(acc, 16); acc += __shfl_xor(acc, 32);
    if (lane == 0) bias_tab[i * NHEADS + h] = 16.f / (1.f + __expf(-acc));
  }
}

// ---------------- combined bias: cb[w][h][n][m] = rpb + mask (fp32, x4 vectorized) ----------------
__global__ __launch_bounds__(256) void cbias_kernel(const int* __restrict__ rpi,
                                                    const float* __restrict__ bias_tab,
                                                    const float* __restrict__ mask,
                                                    float* __restrict__ cb) {
  int e4 = blockIdx.x * 256 + threadIdx.x;
  if (e4 >= NWIN * NHEADS * NTOK * NTOK / 4) return;
  int m0 = (e4 * 4) % NTOK;
  int t = (e4 * 4) / NTOK;
  int n = t % NTOK; t /= NTOK;
  int h = t % NHEADS;
  int w = t / NHEADS;
  int4 idx = *(const int4*)(rpi + n * NTOK + m0);
  float4 mk = *(const float4*)(mask + ((size_t)(w * NTOK + n)) * NTOK + m0);
  float4 r;
  r.x = bias_tab[idx.x * NHEADS + h] + mk.x;
  r.y = bias_tab[idx.y * NHEADS + h] + mk.y;
  r.z = bias_tab[idx.z * NHEADS + h] + mk.z;
  r.w = bias_tab[idx.w * NHEADS + h] + mk.w;
  *(float4*)(cb + (size_t)e4 * 4) = r;
}

// ---------------- fused QKV-projection + cosine attention per (window b, head-PAIR hp) ----------------
// 576 threads = 9 waves; wave wv owns query rows [16wv, 16wv+16).
// R20 == R17 verbatim (best proven: 326us total / 251us attn / absmax 0.015625).
// Falsified-and-reverted since: R18 exp2+deferred-sum (+10us), R19 fused x-cvt (+42us),
// R16 PV-swap (NaN). Structure converged: R14 2-head neutral, R15 depth-2 neutral,
// occupancy 1 vs 3 blocks/CU identical (R13/R17).
__global__ __launch_bounds__(576) void attn_fused(
    const u16* __restrict__ xb, const u16* __restrict__ wb,
    const float* __restrict__ q_bias, const float* __restrict__ k_bias,
    const float* __restrict__ v_bias, const float* __restrict__ cb,
    const float* __restrict__ scalev, u16* __restrict__ ctx) {
  __shared__ u16 smem[22656];  // 45312 B
  u16* qn = smem;               // [144][40] (per-head phases 2+)
  u16* kn = smem + 5760;        // [144][40]
  u16* vT = smem + 11520;       // [32][168]
  u16* Pc = smem + 16896;       // [144][40] (phase 5, wave-private rows)
  u16* xs = smem;               // phase 1: [144][64] half-buffered x rows (18432 B)
  u16* wsm = smem + 9216;       // phase 1: [192][64] half-buffered W rows, 2 heads (24576 B)

  // w-grouped XCD decode: XCD x owns mask-windows {2x,2x+1}; cb set = 2.4MB < 4MB L2
  int bid = blockIdx.x;
  int xcd = bid & 7;
  int i = bid >> 3;          // 0..383
  int wsub = i / 192;        // 0..1
  int j = i - wsub * 192;    // 0..191
  int bI = j / 6;            // 0..31
  int hp = j - bI * 6;       // 0..5 head pair
  int w = xcd * 2 + wsub;
  int b = bI * NWIN + w;
  int h0 = hp * 2;

  int tid = threadIdx.x;
  int lane = tid & 63, wv = tid >> 6;   // wv 0..8
  int g = lane >> 4, c = lane & 15;
  int rbase = wv * 16;

  // ---- phase 1: QKV for BOTH heads, K chunked by 32, prefetch depth 2 ----
  f32x4 acc[2][6];
#pragma unroll
  for (int hh = 0; hh < 2; ++hh)
#pragma unroll
    for (int d = 0; d < 6; ++d) acc[hh][d] = (f32x4){0.f, 0.f, 0.f, 0.f};

  int r4 = tid >> 2, b4 = tid & 3;   // x/W0 row r4, 16B content chunk b4
  bool hasW1 = tid < 192;            // W rows 144..191 on threads 0..191
  int wr1 = 144 + r4;
  int wg0 = (r4 >> 6) * DIMC + (h0 + ((r4 >> 5) & 1)) * 32 + (r4 & 31);
  int wg1 = (wr1 >> 6) * DIMC + (h0 + ((wr1 >> 5) & 1)) * 32 + (wr1 & 31);
  const u16* xg = xb + ((size_t)b * NTOK + r4) * DIMC + b4 * 8;
  const u16* wgp0 = wb + (size_t)wg0 * DIMC + b4 * 8;
  const u16* wgp1 = wb + (size_t)wg1 * DIMC + b4 * 8;
  // half-buffer slots: content chunk (b4 + 4*parity), slot = chunk ^ (row&7)
  int xo0 = r4 * 64 + 8 * (b4 ^ (r4 & 7));
  int xo1 = r4 * 64 + 8 * ((b4 + 4) ^ (r4 & 7));
  int w1o0 = wr1 * 64 + 8 * (b4 ^ (wr1 & 7));
  int w1o1 = wr1 * 64 + 8 * ((b4 + 4) ^ (wr1 & 7));

  // named depth-2 buffers (A = even tiles, B = odd tiles)
  uint4 pxA, pw0A, pw1A, pxB, pw0B, pw1B;
  pxA = *(const uint4*)(xg);
  pw0A = *(const uint4*)(wgp0);
  if (hasW1) pw1A = *(const uint4*)(wgp1);
  pxB = *(const uint4*)(xg + 32);
  pw0B = *(const uint4*)(wgp0 + 32);
  if (hasW1) pw1B = *(const uint4*)(wgp1 + 32);

#pragma unroll
  for (int tt = 0; tt < 6; ++tt) {
    // ---- even sub-iter: tile t=2tt (half 0) ----
    *(uint4*)(xs + xo0) = pxA;
    *(uint4*)(wsm + xo0) = pw0A;
    if (hasW1) *(uint4*)(wsm + w1o0) = pw1A;
    __syncthreads();
    if (tt < 5) {  // issue loads for tile 2tt+2 (2 iterations of cover)
      int k0 = (2 * tt + 2) * 32;
      pxA = *(const uint4*)(xg + k0);
      pw0A = *(const uint4*)(wgp0 + k0);
      if (hasW1) pw1A = *(const uint4*)(wgp1 + k0);
    }
    {
      int arow = rbase + c;
      short8 ax = *(const short8*)(xs + arow * 64 + 8 * (g ^ (arow & 7)));
#pragma unroll
      for (int hh = 0; hh < 2; ++hh)
#pragma unroll
        for (int d = 0; d < 6; ++d) {
          int row = (d >> 1) * 64 + hh * 32 + (d & 1) * 16 + c;
          short8 bw = *(const short8*)(wsm + row * 64 + 8 * (g ^ (row & 7)));
          acc[hh][d] = MFMA(ax, bw, acc[hh][d]);
        }
    }
    // ---- odd sub-iter: tile t=2tt+1 (half 1) ----
    *(uint4*)(xs + xo1) = pxB;
    *(uint4*)(wsm + xo1) = pw0B;
    if (hasW1) *(uint4*)(wsm + w1o1) = pw1B;
    __syncthreads();
    if (tt < 5) {  // issue loads for tile 2tt+3
      int k0 = (2 * tt + 3) * 32;
      pxB = *(const uint4*)(xg + k0);
      pw0B = *(const uint4*)(wgp0 + k0);
      if (hasW1) pw1B = *(const uint4*)(wgp1 + k0);
    }
    {
      int arow = rbase + c;
      short8 ax = *(const short8*)(xs + arow * 64 + 8 * ((g + 4) ^ (arow & 7)));
#pragma unroll
      for (int hh = 0; hh < 2; ++hh)
#pragma unroll
        for (int d = 0; d < 6; ++d) {
          int row = (d >> 1) * 64 + hh * 32 + (d & 1) * 16 + c;
          short8 bw = *(const short8*)(wsm + row * 64 + 8 * ((g + 4) ^ (row & 7)));
          acc[hh][d] = MFMA(ax, bw, acc[hh][d]);
        }
    }
    // no trailing barrier: next sub-iter writes the other half
  }
  __syncthreads();  // phase-1 reads done; smem may be repurposed

  // ---- phases 2-5 per head (sequential, shared buffers) ----
#pragma unroll
  for (int hh = 0; hh < 2; ++hh) {
    int h = h0 + hh;
    if (hh) __syncthreads();  // head B waits for head A's LDS reads

    // phase 2: bias + cosine-normalize in-register, write qn/kn (f2bf) + vT (packed)
    float sch = scalev[h];
    float qb0 = q_bias[h * 32 + c], qb1 = q_bias[h * 32 + 16 + c];
    float kb0 = k_bias[h * 32 + c], kb1 = k_bias[h * 32 + 16 + c];
    float vb0 = v_bias[h * 32 + c], vb1 = v_bias[h * 32 + 16 + c];
    float v0a[4], v1a[4];
#pragma unroll
    for (int r = 0; r < 4; ++r) {
      int row = rbase + g * 4 + r;
      float q0 = acc[hh][0][r] + qb0, q1 = acc[hh][1][r] + qb1;
      float ssq = q0 * q0 + q1 * q1;
      ssq += __shfl_xor(ssq, 1); ssq += __shfl_xor(ssq, 2);
      ssq += __shfl_xor(ssq, 4); ssq += __shfl_xor(ssq, 8);
      float siq = sch / sqrtf(ssq);
      qn[row * 40 + c] = f2bf(q0 * siq);
      qn[row * 40 + 16 + c] = f2bf(q1 * siq);
      float k0v = acc[hh][2][r] + kb0, k1v = acc[hh][3][r] + kb1;
      float ssk = k0v * k0v + k1v * k1v;
      ssk += __shfl_xor(ssk, 1); ssk += __shfl_xor(ssk, 2);
      ssk += __shfl_xor(ssk, 4); ssk += __shfl_xor(ssk, 8);
      float sik = 1.f / sqrtf(ssk);
      kn[row * 40 + c] = f2bf(k0v * sik);
      kn[row * 40 + 16 + c] = f2bf(k1v * sik);
      v0a[r] = acc[hh][4][r] + vb0;
      v1a[r] = acc[hh][5][r] + vb1;
    }
    {  // packed vT writes
      int m0 = rbase + g * 4;
      u16* p0 = vT + c * 168 + m0;
      u16* p1 = vT + (16 + c) * 168 + m0;
      *(u32*)p0 = cvtpk(v0a[0], v0a[1]);
      *(u32*)(p0 + 2) = cvtpk(v0a[2], v0a[3]);
      *(u32*)p1 = cvtpk(v1a[0], v1a[1]);
      *(u32*)(p1 + 2) = cvtpk(v1a[2], v1a[3]);
    }
    if (hh == 0 && tid < 32) {  // zero vT m-pad (144..167) once
      uint4 z4 = {0u, 0u, 0u, 0u};
      *(uint4*)(vT + tid * 168 + 144) = z4;
      *(uint4*)(vT + tid * 168 + 152) = z4;
      *(uint4*)(vT + tid * 168 + 160) = z4;
    }
    __syncthreads();

    // phase 3: S = qn . kn^T
    short8 aq = *(const short8*)(qn + (rbase + c) * 40 + g * 8);
    f32x4 S[9];
#pragma unroll
    for (int mt = 0; mt < 9; ++mt) {
      short8 bk = *(const short8*)(kn + (mt * 16 + c) * 40 + g * 8);
      f32x4 z = (f32x4){0.f, 0.f, 0.f, 0.f};
      S[mt] = MFMA(aq, bk, z);
    }

    // phase 4: + (rpb + mask), row softmax (folded 1/sum into P)
    const float* cbh = cb + (((size_t)w * NHEADS + h) * NTOK) * NTOK;
#pragma unroll
    for (int r = 0; r < 4; ++r) {
      int row = rbase + g * 4 + r;
      const float* crow = cbh + (size_t)row * NTOK + c;
      float sv[9];
      float mx = -1e30f;
#pragma unroll
      for (int mt = 0; mt < 9; ++mt) {
        float s = S[mt][r] + crow[mt * 16];
        sv[mt] = s;
        mx = fmaxf(mx, s);
      }
      mx = fmaxf(mx, __shfl_xor(mx, 1)); mx = fmaxf(mx, __shfl_xor(mx, 2));
      mx = fmaxf(mx, __shfl_xor(mx, 4)); mx = fmaxf(mx, __shfl_xor(mx, 8));
      float sum = 0.f;
#pragma unroll
      for (int mt = 0; mt < 9; ++mt) {
        float p = __expf(sv[mt] - mx);
        sv[mt] = p;
        sum += p;
      }
      sum += __shfl_xor(sum, 1); sum += __shfl_xor(sum, 2);
      sum += __shfl_xor(sum, 4); sum += __shfl_xor(sum, 8);
      float rinv = 1.f / sum;
#pragma unroll
      for (int mt = 0; mt < 9; ++mt) S[mt][r] = sv[mt] * rinv;
    }

    // phase 5: PV via per-wave P bounce (wave-private Pc rows, no barriers)
    f32x4 po[2];
    po[0] = (f32x4){0.f, 0.f, 0.f, 0.f};
    po[1] = (f32x4){0.f, 0.f, 0.f, 0.f};
    for (int ck = 0; ck < 5; ++ck) {
#pragma unroll
      for (int mt2 = 0; mt2 < 2; ++mt2) {
        int MT = ck * 2 + mt2;
#pragma unroll
        for (int r = 0; r < 4; ++r) {
          int row = rbase + g * 4 + r;
          float p = (MT < 9) ? S[MT][r] : 0.f;
          Pc[row * 40 + mt2 * 16 + c] = f2bf(p);
        }
      }
      short8 pa = *(const short8*)(Pc + (rbase + c) * 40 + g * 8);
#pragma unroll
      for (int dt = 0; dt < 2; ++dt) {
        short8 vb = *(const short8*)(vT + (dt * 16 + c) * 168 + ck * 32 + g * 8);
        po[dt] = MFMA(pa, vb, po[dt]);
      }
    }

    // epilogue: ctx[b*144+n][h*32+d] bf16
#pragma unroll
    for (int dt = 0; dt < 2; ++dt)
#pragma unroll
      for (int r = 0; r < 4; ++r) {
        int n = rbase + g * 4 + r;
        ctx[((size_t)b * NTOK + n) * DIMC + h * 32 + dt * 16 + c] = f2bf(po[dt][r]);
      }
  }
}

// ---------------- output projection: (73728 x 384) @ (384 x 384)^T + bias, bf16 MFMA ----------------
__global__ __launch_bounds__(256) void proj_gemm(const u16* __restrict__ ctx,
                                                 const u16* __restrict__ pwb,
                                                 const float* __restrict__ proj_b,
                                                 float* __restrict__ out) {
  __shared__ u16 As[128 * 64];
  __shared__ u16 Bs[128 * 64];
  int bid = blockIdx.x;
  int nblk = bid % 3, mblk = bid / 3;
  size_t gm0 = (size_t)mblk * 128;
  int gn0 = nblk * 128;
  int tid = threadIdx.x, lane = tid & 63, wid = tid >> 6;
  int wr = wid >> 1, wc = wid & 1, g = lane >> 4, c = lane & 15;
  f32x4 acc[4][4];
#pragma unroll
  for (int i = 0; i < 4; ++i)
#pragma unroll
    for (int j = 0; j < 4; ++j) acc[i][j] = (f32x4){0.f, 0.f, 0.f, 0.f};

  for (int t = 0; t < 6; ++t) {
    int k0 = t * 64;
#pragma unroll
    for (int p = 0; p < 4; ++p) {
      int row = p * 32 + (tid >> 3);
      int seg = (tid & 7) * 8;
      uint4 va = *(const uint4*)(ctx + (gm0 + row) * DIMC + k0 + seg);
      *(uint4*)(As + row * 64 + seg) = va;
      uint4 vb = *(const uint4*)(pwb + (size_t)(gn0 + row) * DIMC + k0 + seg);
      *(uint4*)(Bs + row * 64 + seg) = vb;
    }
    __syncthreads();
#pragma unroll
    for (int kk = 0; kk < 64; kk += 32) {
      short8 a[4], bfr[4];
#pragma unroll
      for (int mi = 0; mi < 4; ++mi)
        a[mi] = *(const short8*)(As + (wr * 64 + mi * 16 + c) * 64 + kk + g * 8);
#pragma unroll
      for (int ni = 0; ni < 4; ++ni)
        bfr[ni] = *(const short8*)(Bs + (wc * 64 + ni * 16 + c) * 64 + kk + g * 8);
#pragma unroll
      for (int mi = 0; mi < 4; ++mi)
#pragma unroll
        for (int ni = 0; ni < 4; ++ni)
          acc[mi][ni] = MFMA(a[mi], bfr[ni], acc[mi][ni]);
    }
    __syncthreads();
  }
#pragma unroll
  for (int mi = 0; mi < 4; ++mi)
#pragma unroll
    for (int ni = 0; ni < 4; ++ni) {
      int gcol = gn0 + wc * 64 + ni * 16 + c;
      float bv = proj_b[gcol];
#pragma unroll
      for (int r = 0; r < 4; ++r) {
        size_t grow = gm0 + wr * 64 + mi * 16 + g * 4 + r;
        out[grow * DIMC + gcol] = acc[mi][ni][r] + bv;
      }
    }
}

extern "C" void kernel_launch(void* const* d_in, const int* in_sizes, int n_in,
                              void* d_out, int out_size, void* d_ws, size_t ws_size,
                              hipStream_t stream) {
  const float* x = (const float*)d_in[0];
  const float* rct = (const float*)d_in[1];
  const int* rpi = (const int*)d_in[2];
  const float* mask = (const float*)d_in[3];
  const float* qkv_w = (const float*)d_in[4];
  const float* q_bias = (const float*)d_in[5];
  const float* k_bias = (const float*)d_in[6];
  const float* v_bias = (const float*)d_in[7];
  const float* logit_scale = (const float*)d_in[8];
  const float* cpb_w1 = (const float*)d_in[9];
  const float* cpb_b1 = (const float*)d_in[10];
  const float* cpb_w2 = (const float*)d_in[11];
  const float* proj_w = (const float*)d_in[12];
  const float* proj_b = (const float*)d_in[13];
  float* out = (float*)d_out;

  char* ws = (char*)d_ws;
  size_t off = 0;
  auto alloc = [&](size_t bytes) {
    void* p = ws + off;
    off = (off + bytes + 255) & ~(size_t)255;
    return p;
  };
  const size_t NX = (size_t)BWIN * NTOK * DIMC;  // 28311552
  u16* xb = (u16*)alloc(NX * 2);
  u16* wqb = (u16*)alloc((size_t)3 * DIMC * DIMC * 2);
  u16* pwb = (u16*)alloc((size_t)DIMC * DIMC * 2);
  u16* ctx = (u16*)alloc(NX * 2);
  float* cbv = (float*)alloc((size_t)NWIN * NHEADS * NTOK * NTOK * 4);
  float* bias_tab = (float*)alloc((size_t)TABLEN * NHEADS * 4);
  float* scalev = (float*)alloc(64 * 4);

  cvt_bf16<<<(int)(NX / 8 + 255) / 256, 256, 0, stream>>>(x, xb, (int)(NX / 8));
  cvt_bf16<<<(3 * DIMC * DIMC / 8 + 255) / 256, 256, 0, stream>>>(qkv_w, wqb, 3 * DIMC * DIMC / 8);
  cvt_bf16<<<(DIMC * DIMC / 8 + 255) / 256, 256, 0, stream>>>(proj_w, pwb, DIMC * DIMC / 8);
  cpb_kernel<<<TABLEN, 256, 0, stream>>>(
      rct, cpb_w1, cpb_b1, cpb_w2, logit_scale, bias_tab, scalev);
  cbias_kernel<<<(NWIN * NHEADS * NTOK * NTOK / 4 + 255) / 256, 256, 0, stream>>>(
      rpi, bias_tab, mask, cbv);
  attn_fused<<<BWIN * 6, 576, 0, stream>>>(
      xb, wqb, q_bias, k_bias, v_bias, cbv, scalev, ctx);
  proj_gemm<<<(BWIN * NTOK / 128) * 3, 256, 0, stream>>>(ctx, pwb, proj_b, out);
}

// Round 21
// 316.255 us; speedup vs baseline: 1.0528x; 1.0256x over previous
//
#include <hip/hip_runtime.h>

#define DIMC 384
#define NHEADS 12
#define NTOK 144
#define TABLEN 529
#define BWIN 512
#define NWIN 16
#define CPBH 512

typedef unsigned short u16;
typedef unsigned int u32;
typedef __attribute__((ext_vector_type(8))) short short8;
typedef __attribute__((ext_vector_type(4))) float f32x4;

#define MFMA(a, b, c) __builtin_amdgcn_mfma_f32_16x16x32_bf16((a), (b), (c), 0, 0, 0)

__device__ __forceinline__ u16 f2bf(float f) {
  union { float f; u32 u; } v; v.f = f;
  u32 r = v.u + 0x7fffu + ((v.u >> 16) & 1u);
  return (u16)(r >> 16);
}
__device__ __forceinline__ u32 pk2(float a, float b) {
  return (u32)f2bf(a) | ((u32)f2bf(b) << 16);
}
__device__ __forceinline__ u32 cvtpk(float lo, float hi) {
  u32 r;
  asm("v_cvt_pk_bf16_f32 %0, %1, %2" : "=v"(r) : "v"(lo), "v"(hi));
  return r;
}

// ---------------- f32 -> bf16 bulk convert ----------------
__global__ __launch_bounds__(256) void cvt_bf16(const float* __restrict__ in,
                                                u16* __restrict__ out, int n8) {
  int i = blockIdx.x * 256 + threadIdx.x;
  if (i >= n8) return;
  const float4* p = (const float4*)(in + (size_t)i * 8);
  float4 a = p[0], b = p[1];
  uint4 r;
  r.x = pk2(a.x, a.y); r.y = pk2(a.z, a.w);
  r.z = pk2(b.x, b.y); r.w = pk2(b.z, b.w);
  *(uint4*)(out + (size_t)i * 8) = r;
}

// ---------------- CPB-MLP table: one block per table entry i (529 blocks, R17-proven) ----------------
__global__ __launch_bounds__(256) void cpb_kernel(const float* __restrict__ rct,
                                                  const float* __restrict__ w1,
                                                  const float* __restrict__ b1,
                                                  const float* __restrict__ w2,
                                                  const float* __restrict__ logit_scale,
                                                  float* __restrict__ bias_tab,
                                                  float* __restrict__ scalev) {
  __shared__ float h1[CPBH];
  int i = blockIdx.x;
  int tid = threadIdx.x;
  if (i == 0 && tid < NHEADS)
    scalev[tid] = __expf(fminf(logit_scale[tid], 4.60517018598809f));
  float c0 = rct[2 * i], c1 = rct[2 * i + 1];
  for (int k = tid; k < CPBH; k += 256)
    h1[k] = fmaxf(0.f, fmaf(c0, w1[2 * k], fmaf(c1, w1[2 * k + 1], b1[k])));
  __syncthreads();
  int wv = tid >> 6, lane = tid & 63;
#pragma unroll
  for (int hh = 0; hh < 3; ++hh) {
    int h = wv * 3 + hh;
    const float* w2h = w2 + (size_t)h * CPBH;
    float acc = 0.f;
#pragma unroll
    for (int k = 0; k < CPBH; k += 64) acc = fmaf(h1[k + lane], w2h[k + lane], acc);
    acc += __shfl_xor(acc, 1); acc += __shfl_xor(acc, 2); acc += __shfl_xor(acc, 4);
    acc += __shfl_xor(acc, 8); acc += __shfl_xor(acc, 16); acc += __shfl_xor(acc, 32);
    if (lane == 0) bias_tab[i * NHEADS + h] = 16.f / (1.f + __expf(-acc));
  }
}

// ---------------- combined bias: cb[w][h][n][m] = rpb + mask (fp32, x4 vectorized) ----------------
__global__ __launch_bounds__(256) void cbias_kernel(const int* __restrict__ rpi,
                                                    const float* __restrict__ bias_tab,
                                                    const float* __restrict__ mask,
                                                    float* __restrict__ cb) {
  int e4 = blockIdx.x * 256 + threadIdx.x;
  if (e4 >= NWIN * NHEADS * NTOK * NTOK / 4) return;
  int m0 = (e4 * 4) % NTOK;
  int t = (e4 * 4) / NTOK;
  int n = t % NTOK; t /= NTOK;
  int h = t % NHEADS;
  int w = t / NHEADS;
  int4 idx = *(const int4*)(rpi + n * NTOK + m0);
  float4 mk = *(const float4*)(mask + ((size_t)(w * NTOK + n)) * NTOK + m0);
  float4 r;
  r.x = bias_tab[idx.x * NHEADS + h] + mk.x;
  r.y = bias_tab[idx.y * NHEADS + h] + mk.y;
  r.z = bias_tab[idx.z * NHEADS + h] + mk.z;
  r.w = bias_tab[idx.w * NHEADS + h] + mk.w;
  *(float4*)(cb + (size_t)e4 * 4) = r;
}

// ---------------- fused QKV-projection + cosine attention per (window b, head-PAIR hp) ----------------
// 576 threads = 9 waves.
// R21 (single change vs R20): phase-1 waves form a 3x3 tile grid — wave (wr3,wc3)
// owns 48 rows x 64 cols. Per K=32 iteration each wave reads 3 ax + 4 bw = 7
// ds_read_b128 (was 1+12=13): -46% phase-1 LDS reads, same 12 MFMA, same 48-VGPR acc.
// Col partition makes wc3=0/1/2 waves own exactly q/k/v (W LDS rows are 32-row
// blocks [q h0|q h1|k h0|k h1|v h0|v h1]); phase 2 is role-specialized,
// wave-uniform branches, identical shfl reductions. Phases 3-5 = R20-verbatim.
__global__ __launch_bounds__(576) void attn_fused(
    const u16* __restrict__ xb, const u16* __restrict__ wb,
    const float* __restrict__ q_bias, const float* __restrict__ k_bias,
    const float* __restrict__ v_bias, const float* __restrict__ cb,
    const float* __restrict__ scalev, u16* __restrict__ ctx) {
  __shared__ u16 smem[22656];  // 45312 B
  u16* qn = smem;               // [144][40] (per-head phases 2+)
  u16* kn = smem + 5760;        // [144][40]
  u16* vT = smem + 11520;       // [32][168]
  u16* Pc = smem + 16896;       // [144][40] (phase 5, wave-private rows)
  u16* xs = smem;               // phase 1: [144][64] half-buffered x rows (18432 B)
  u16* wsm = smem + 9216;       // phase 1: [192][64] half-buffered W rows, 2 heads (24576 B)

  // w-grouped XCD decode: XCD x owns mask-windows {2x,2x+1}; cb set = 2.4MB < 4MB L2
  int bid = blockIdx.x;
  int xcd = bid & 7;
  int i = bid >> 3;          // 0..383
  int wsub = i / 192;        // 0..1
  int j = i - wsub * 192;    // 0..191
  int bI = j / 6;            // 0..31
  int hp = j - bI * 6;       // 0..5 head pair
  int w = xcd * 2 + wsub;
  int b = bI * NWIN + w;
  int h0 = hp * 2;

  int tid = threadIdx.x;
  int lane = tid & 63, wv = tid >> 6;   // wv 0..8
  int g = lane >> 4, c = lane & 15;
  int rbase = wv * 16;                  // phases 3-5 row ownership (unchanged)
  int wr3 = wv / 3, wc3 = wv % 3;       // phase-1/2 tile: rows wr3*48.., cols wc3*64..

  // ---- phase 1: QKV for BOTH heads, K chunked by 32, prefetch depth 2, 3x3 wave grid ----
  f32x4 acc[3][4];
#pragma unroll
  for (int mi = 0; mi < 3; ++mi)
#pragma unroll
    for (int ni = 0; ni < 4; ++ni) acc[mi][ni] = (f32x4){0.f, 0.f, 0.f, 0.f};

  int r4 = tid >> 2, b4 = tid & 3;   // x/W0 row r4, 16B content chunk b4
  bool hasW1 = tid < 192;            // W rows 144..191 on threads 0..191
  int wr1 = 144 + r4;
  int wg0 = (r4 >> 6) * DIMC + (h0 + ((r4 >> 5) & 1)) * 32 + (r4 & 31);
  int wg1 = (wr1 >> 6) * DIMC + (h0 + ((wr1 >> 5) & 1)) * 32 + (wr1 & 31);
  const u16* xg = xb + ((size_t)b * NTOK + r4) * DIMC + b4 * 8;
  const u16* wgp0 = wb + (size_t)wg0 * DIMC + b4 * 8;
  const u16* wgp1 = wb + (size_t)wg1 * DIMC + b4 * 8;
  // half-buffer slots: content chunk (b4 + 4*parity), slot = chunk ^ (row&7)
  int xo0 = r4 * 64 + 8 * (b4 ^ (r4 & 7));
  int xo1 = r4 * 64 + 8 * ((b4 + 4) ^ (r4 & 7));
  int w1o0 = wr1 * 64 + 8 * (b4 ^ (wr1 & 7));
  int w1o1 = wr1 * 64 + 8 * ((b4 + 4) ^ (wr1 & 7));

  // named depth-2 buffers (A = even tiles, B = odd tiles)
  uint4 pxA, pw0A, pw1A, pxB, pw0B, pw1B;
  pxA = *(const uint4*)(xg);
  pw0A = *(const uint4*)(wgp0);
  if (hasW1) pw1A = *(const uint4*)(wgp1);
  pxB = *(const uint4*)(xg + 32);
  pw0B = *(const uint4*)(wgp0 + 32);
  if (hasW1) pw1B = *(const uint4*)(wgp1 + 32);

#pragma unroll
  for (int tt = 0; tt < 6; ++tt) {
    // ---- even sub-iter: tile t=2tt (half 0) ----
    *(uint4*)(xs + xo0) = pxA;
    *(uint4*)(wsm + xo0) = pw0A;
    if (hasW1) *(uint4*)(wsm + w1o0) = pw1A;
    __syncthreads();
    if (tt < 5) {  // issue loads for tile 2tt+2 (2 iterations of cover)
      int k0 = (2 * tt + 2) * 32;
      pxA = *(const uint4*)(xg + k0);
      pw0A = *(const uint4*)(wgp0 + k0);
      if (hasW1) pw1A = *(const uint4*)(wgp1 + k0);
    }
    {
      short8 ax[3];
#pragma unroll
      for (int mi = 0; mi < 3; ++mi) {
        int arow = wr3 * 48 + mi * 16 + c;
        ax[mi] = *(const short8*)(xs + arow * 64 + 8 * (g ^ (arow & 7)));
      }
#pragma unroll
      for (int ni = 0; ni < 4; ++ni) {
        int row = wc3 * 64 + ni * 16 + c;
        short8 bw = *(const short8*)(wsm + row * 64 + 8 * (g ^ (row & 7)));
#pragma unroll
        for (int mi = 0; mi < 3; ++mi) acc[mi][ni] = MFMA(ax[mi], bw, acc[mi][ni]);
      }
    }
    // ---- odd sub-iter: tile t=2tt+1 (half 1) ----
    *(uint4*)(xs + xo1) = pxB;
    *(uint4*)(wsm + xo1) = pw0B;
    if (hasW1) *(uint4*)(wsm + w1o1) = pw1B;
    __syncthreads();
    if (tt < 5) {  // issue loads for tile 2tt+3
      int k0 = (2 * tt + 3) * 32;
      pxB = *(const uint4*)(xg + k0);
      pw0B = *(const uint4*)(wgp0 + k0);
      if (hasW1) pw1B = *(const uint4*)(wgp1 + k0);
    }
    {
      short8 ax[3];
#pragma unroll
      for (int mi = 0; mi < 3; ++mi) {
        int arow = wr3 * 48 + mi * 16 + c;
        ax[mi] = *(const short8*)(xs + arow * 64 + 8 * ((g + 4) ^ (arow & 7)));
      }
#pragma unroll
      for (int ni = 0; ni < 4; ++ni) {
        int row = wc3 * 64 + ni * 16 + c;
        short8 bw = *(const short8*)(wsm + row * 64 + 8 * ((g + 4) ^ (row & 7)));
#pragma unroll
        for (int mi = 0; mi < 3; ++mi) acc[mi][ni] = MFMA(ax[mi], bw, acc[mi][ni]);
      }
    }
    // no trailing barrier: next sub-iter writes the other half
  }
  __syncthreads();  // phase-1 reads done; smem may be repurposed

  // ---- phases 2-5 per head (sequential, shared buffers) ----
#pragma unroll
  for (int hh = 0; hh < 2; ++hh) {
    int h = h0 + hh;
    if (hh) __syncthreads();  // head B waits for head A's LDS reads

    // phase 2 (role-specialized): wc3=0 -> qn, wc3=1 -> kn, wc3=2 -> vT.
    // acc[mi][hh*2 + t] holds head hh, col16 half t, rows wr3*48+mi*16+g*4+r.
    float sch = scalev[h];
    if (wc3 == 0) {
      float qb0 = q_bias[h * 32 + c], qb1 = q_bias[h * 32 + 16 + c];
#pragma unroll
      for (int mi = 0; mi < 3; ++mi) {
#pragma unroll
        for (int r = 0; r < 4; ++r) {
          int row = wr3 * 48 + mi * 16 + g * 4 + r;
          float q0 = acc[mi][hh * 2][r] + qb0, q1 = acc[mi][hh * 2 + 1][r] + qb1;
          float ssq = q0 * q0 + q1 * q1;
          ssq += __shfl_xor(ssq, 1); ssq += __shfl_xor(ssq, 2);
          ssq += __shfl_xor(ssq, 4); ssq += __shfl_xor(ssq, 8);
          float siq = sch / sqrtf(ssq);
          qn[row * 40 + c] = f2bf(q0 * siq);
          qn[row * 40 + 16 + c] = f2bf(q1 * siq);
        }
      }
    } else if (wc3 == 1) {
      float kb0 = k_bias[h * 32 + c], kb1 = k_bias[h * 32 + 16 + c];
#pragma unroll
      for (int mi = 0; mi < 3; ++mi) {
#pragma unroll
        for (int r = 0; r < 4; ++r) {
          int row = wr3 * 48 + mi * 16 + g * 4 + r;
          float k0v = acc[mi][hh * 2][r] + kb0, k1v = acc[mi][hh * 2 + 1][r] + kb1;
          float ssk = k0v * k0v + k1v * k1v;
          ssk += __shfl_xor(ssk, 1); ssk += __shfl_xor(ssk, 2);
          ssk += __shfl_xor(ssk, 4); ssk += __shfl_xor(ssk, 8);
          float sik = 1.f / sqrtf(ssk);
          kn[row * 40 + c] = f2bf(k0v * sik);
          kn[row * 40 + 16 + c] = f2bf(k1v * sik);
        }
      }
    } else {
      float vb0 = v_bias[h * 32 + c], vb1 = v_bias[h * 32 + 16 + c];
#pragma unroll
      for (int mi = 0; mi < 3; ++mi) {
        float v0a[4], v1a[4];
#pragma unroll
        for (int r = 0; r < 4; ++r) {
          v0a[r] = acc[mi][hh * 2][r] + vb0;
          v1a[r] = acc[mi][hh * 2 + 1][r] + vb1;
        }
        int m0 = wr3 * 48 + mi * 16 + g * 4;
        u16* p0 = vT + c * 168 + m0;
        u16* p1 = vT + (16 + c) * 168 + m0;
        *(u32*)p0 = cvtpk(v0a[0], v0a[1]);
        *(u32*)(p0 + 2) = cvtpk(v0a[2], v0a[3]);
        *(u32*)p1 = cvtpk(v1a[0], v1a[1]);
        *(u32*)(p1 + 2) = cvtpk(v1a[2], v1a[3]);
      }
    }
    if (hh == 0 && tid < 32) {  // zero vT m-pad (144..167) once
      uint4 z4 = {0u, 0u, 0u, 0u};
      *(uint4*)(vT + tid * 168 + 144) = z4;
      *(uint4*)(vT + tid * 168 + 152) = z4;
      *(uint4*)(vT + tid * 168 + 160) = z4;
    }
    __syncthreads();

    // phase 3: S = qn . kn^T (R20-verbatim)
    short8 aq = *(const short8*)(qn + (rbase + c) * 40 + g * 8);
    f32x4 S[9];
#pragma unroll
    for (int mt = 0; mt < 9; ++mt) {
      short8 bk = *(const short8*)(kn + (mt * 16 + c) * 40 + g * 8);
      f32x4 z = (f32x4){0.f, 0.f, 0.f, 0.f};
      S[mt] = MFMA(aq, bk, z);
    }

    // phase 4: + (rpb + mask), row softmax (folded 1/sum into P) (R20-verbatim)
    const float* cbh = cb + (((size_t)w * NHEADS + h) * NTOK) * NTOK;
#pragma unroll
    for (int r = 0; r < 4; ++r) {
      int row = rbase + g * 4 + r;
      const float* crow = cbh + (size_t)row * NTOK + c;
      float sv[9];
      float mx = -1e30f;
#pragma unroll
      for (int mt = 0; mt < 9; ++mt) {
        float s = S[mt][r] + crow[mt * 16];
        sv[mt] = s;
        mx = fmaxf(mx, s);
      }
      mx = fmaxf(mx, __shfl_xor(mx, 1)); mx = fmaxf(mx, __shfl_xor(mx, 2));
      mx = fmaxf(mx, __shfl_xor(mx, 4)); mx = fmaxf(mx, __shfl_xor(mx, 8));
      float sum = 0.f;
#pragma unroll
      for (int mt = 0; mt < 9; ++mt) {
        float p = __expf(sv[mt] - mx);
        sv[mt] = p;
        sum += p;
      }
      sum += __shfl_xor(sum, 1); sum += __shfl_xor(sum, 2);
      sum += __shfl_xor(sum, 4); sum += __shfl_xor(sum, 8);
      float rinv = 1.f / sum;
#pragma unroll
      for (int mt = 0; mt < 9; ++mt) S[mt][r] = sv[mt] * rinv;
    }

    // phase 5: PV via per-wave P bounce (R20-verbatim)
    f32x4 po[2];
    po[0] = (f32x4){0.f, 0.f, 0.f, 0.f};
    po[1] = (f32x4){0.f, 0.f, 0.f, 0.f};
    for (int ck = 0; ck < 5; ++ck) {
#pragma unroll
      for (int mt2 = 0; mt2 < 2; ++mt2) {
        int MT = ck * 2 + mt2;
#pragma unroll
        for (int r = 0; r < 4; ++r) {
          int row = rbase + g * 4 + r;
          float p = (MT < 9) ? S[MT][r] : 0.f;
          Pc[row * 40 + mt2 * 16 + c] = f2bf(p);
        }
      }
      short8 pa = *(const short8*)(Pc + (rbase + c) * 40 + g * 8);
#pragma unroll
      for (int dt = 0; dt < 2; ++dt) {
        short8 vb = *(const short8*)(vT + (dt * 16 + c) * 168 + ck * 32 + g * 8);
        po[dt] = MFMA(pa, vb, po[dt]);
      }
    }

    // epilogue: ctx[b*144+n][h*32+d] bf16 (R20-verbatim)
#pragma unroll
    for (int dt = 0; dt < 2; ++dt)
#pragma unroll
      for (int r = 0; r < 4; ++r) {
        int n = rbase + g * 4 + r;
        ctx[((size_t)b * NTOK + n) * DIMC + h * 32 + dt * 16 + c] = f2bf(po[dt][r]);
      }
  }
}

// ---------------- output projection: (73728 x 384) @ (384 x 384)^T + bias, bf16 MFMA ----------------
__global__ __launch_bounds__(256) void proj_gemm(const u16* __restrict__ ctx,
                                                 const u16* __restrict__ pwb,
                                                 const float* __restrict__ proj_b,
                                                 float* __restrict__ out) {
  __shared__ u16 As[128 * 64];
  __shared__ u16 Bs[128 * 64];
  int bid = blockIdx.x;
  int nblk = bid % 3, mblk = bid / 3;
  size_t gm0 = (size_t)mblk * 128;
  int gn0 = nblk * 128;
  int tid = threadIdx.x, lane = tid & 63, wid = tid >> 6;
  int wr = wid >> 1, wc = wid & 1, g = lane >> 4, c = lane & 15;
  f32x4 acc[4][4];
#pragma unroll
  for (int i = 0; i < 4; ++i)
#pragma unroll
    for (int j = 0; j < 4; ++j) acc[i][j] = (f32x4){0.f, 0.f, 0.f, 0.f};

  for (int t = 0; t < 6; ++t) {
    int k0 = t * 64;
#pragma unroll
    for (int p = 0; p < 4; ++p) {
      int row = p * 32 + (tid >> 3);
      int seg = (tid & 7) * 8;
      uint4 va = *(const uint4*)(ctx + (gm0 + row) * DIMC + k0 + seg);
      *(uint4*)(As + row * 64 + seg) = va;
      uint4 vb = *(const uint4*)(pwb + (size_t)(gn0 + row) * DIMC + k0 + seg);
      *(uint4*)(Bs + row * 64 + seg) = vb;
    }
    __syncthreads();
#pragma unroll
    for (int kk = 0; kk < 64; kk += 32) {
      short8 a[4], bfr[4];
#pragma unroll
      for (int mi = 0; mi < 4; ++mi)
        a[mi] = *(const short8*)(As + (wr * 64 + mi * 16 + c) * 64 + kk + g * 8);
#pragma unroll
      for (int ni = 0; ni < 4; ++ni)
        bfr[ni] = *(const short8*)(Bs + (wc * 64 + ni * 16 + c) * 64 + kk + g * 8);
#pragma unroll
      for (int mi = 0; mi < 4; ++mi)
#pragma unroll
        for (int ni = 0; ni < 4; ++ni)
          acc[mi][ni] = MFMA(a[mi], bfr[ni], acc[mi][ni]);
    }
    __syncthreads();
  }
#pragma unroll
  for (int mi = 0; mi < 4; ++mi)
#pragma unroll
    for (int ni = 0; ni < 4; ++ni) {
      int gcol = gn0 + wc * 64 + ni * 16 + c;
      float bv = proj_b[gcol];
#pragma unroll
      for (int r = 0; r < 4; ++r) {
        size_t grow = gm0 + wr * 64 + mi * 16 + g * 4 + r;
        out[grow * DIMC + gcol] = acc[mi][ni][r] + bv;
      }
    }
}

extern "C" void kernel_launch(void* const* d_in, const int* in_sizes, int n_in,
                              void* d_out, int out_size, void* d_ws, size_t ws_size,
                              hipStream_t stream) {
  const float* x = (const float*)d_in[0];
  const float* rct = (const float*)d_in[1];
  const int* rpi = (const int*)d_in[2];
  const float* mask = (const float*)d_in[3];
  const float* qkv_w = (const float*)d_in[4];
  const float* q_bias = (const float*)d_in[5];
  const float* k_bias = (const float*)d_in[6];
  const float* v_bias = (const float*)d_in[7];
  const float* logit_scale = (const float*)d_in[8];
  const float* cpb_w1 = (const float*)d_in[9];
  const float* cpb_b1 = (const float*)d_in[10];
  const float* cpb_w2 = (const float*)d_in[11];
  const float* proj_w = (const float*)d_in[12];
  const float* proj_b = (const float*)d_in[13];
  float* out = (float*)d_out;

  char* ws = (char*)d_ws;
  size_t off = 0;
  auto alloc = [&](size_t bytes) {
    void* p = ws + off;
    off = (off + bytes + 255) & ~(size_t)255;
    return p;
  };
  const size_t NX = (size_t)BWIN * NTOK * DIMC;  // 28311552
  u16* xb = (u16*)alloc(NX * 2);
  u16* wqb = (u16*)alloc((size_t)3 * DIMC * DIMC * 2);
  u16* pwb = (u16*)alloc((size_t)DIMC * DIMC * 2);
  u16* ctx = (u16*)alloc(NX * 2);
  float* cbv = (float*)alloc((size_t)NWIN * NHEADS * NTOK * NTOK * 4);
  float* bias_tab = (float*)alloc((size_t)TABLEN * NHEADS * 4);
  float* scalev = (float*)alloc(64 * 4);

  cvt_bf16<<<(int)(NX / 8 + 255) / 256, 256, 0, stream>>>(x, xb, (int)(NX / 8));
  cvt_bf16<<<(3 * DIMC * DIMC / 8 + 255) / 256, 256, 0, stream>>>(qkv_w, wqb, 3 * DIMC * DIMC / 8);
  cvt_bf16<<<(DIMC * DIMC / 8 + 255) / 256, 256, 0, stream>>>(proj_w, pwb, DIMC * DIMC / 8);
  cpb_kernel<<<TABLEN, 256, 0, stream>>>(
      rct, cpb_w1, cpb_b1, cpb_w2, logit_scale, bias_tab, scalev);
  cbias_kernel<<<(NWIN * NHEADS * NTOK * NTOK / 4 + 255) / 256, 256, 0, stream>>>(
      rpi, bias_tab, mask, cbv);
  attn_fused<<<BWIN * 6, 576, 0, stream>>>(
      xb, wqb, q_bias, k_bias, v_bias, cbv, scalev, ctx);
  proj_gemm<<<(BWIN * NTOK / 128) * 3, 256, 0, stream>>>(ctx, pwb, proj_b, out);
}

// Round 22
// 309.035 us; speedup vs baseline: 1.0774x; 1.0234x over previous
//
#include <hip/hip_runtime.h>

#define DIMC 384
#define NHEADS 12
#define NTOK 144
#define TABLEN 529
#define BWIN 512
#define NWIN 16
#define CPBH 512

typedef unsigned short u16;
typedef unsigned int u32;
typedef __attribute__((ext_vector_type(8))) short short8;
typedef __attribute__((ext_vector_type(4))) float f32x4;

#define MFMA(a, b, c) __builtin_amdgcn_mfma_f32_16x16x32_bf16((a), (b), (c), 0, 0, 0)

__device__ __forceinline__ u16 f2bf(float f) {
  union { float f; u32 u; } v; v.f = f;
  u32 r = v.u + 0x7fffu + ((v.u >> 16) & 1u);
  return (u16)(r >> 16);
}
__device__ __forceinline__ u32 pk2(float a, float b) {
  return (u32)f2bf(a) | ((u32)f2bf(b) << 16);
}
__device__ __forceinline__ u32 cvtpk(float lo, float hi) {
  u32 r;
  asm("v_cvt_pk_bf16_f32 %0, %1, %2" : "=v"(r) : "v"(lo), "v"(hi));
  return r;
}

// ---------------- f32 -> bf16 bulk convert ----------------
__global__ __launch_bounds__(256) void cvt_bf16(const float* __restrict__ in,
                                                u16* __restrict__ out, int n8) {
  int i = blockIdx.x * 256 + threadIdx.x;
  if (i >= n8) return;
  const float4* p = (const float4*)(in + (size_t)i * 8);
  float4 a = p[0], b = p[1];
  uint4 r;
  r.x = pk2(a.x, a.y); r.y = pk2(a.z, a.w);
  r.z = pk2(b.x, b.y); r.w = pk2(b.z, b.w);
  *(uint4*)(out + (size_t)i * 8) = r;
}

// ---------------- CPB-MLP table: one block per table entry i (529 blocks, R17-proven) ----------------
__global__ __launch_bounds__(256) void cpb_kernel(const float* __restrict__ rct,
                                                  const float* __restrict__ w1,
                                                  const float* __restrict__ b1,
                                                  const float* __restrict__ w2,
                                                  const float* __restrict__ logit_scale,
                                                  float* __restrict__ bias_tab,
                                                  float* __restrict__ scalev) {
  __shared__ float h1[CPBH];
  int i = blockIdx.x;
  int tid = threadIdx.x;
  if (i == 0 && tid < NHEADS)
    scalev[tid] = __expf(fminf(logit_scale[tid], 4.60517018598809f));
  float c0 = rct[2 * i], c1 = rct[2 * i + 1];
  for (int k = tid; k < CPBH; k += 256)
    h1[k] = fmaxf(0.f, fmaf(c0, w1[2 * k], fmaf(c1, w1[2 * k + 1], b1[k])));
  __syncthreads();
  int wv = tid >> 6, lane = tid & 63;
#pragma unroll
  for (int hh = 0; hh < 3; ++hh) {
    int h = wv * 3 + hh;
    const float* w2h = w2 + (size_t)h * CPBH;
    float acc = 0.f;
#pragma unroll
    for (int k = 0; k < CPBH; k += 64) acc = fmaf(h1[k + lane], w2h[k + lane], acc);
    acc += __shfl_xor(acc, 1); acc += __shfl_xor(acc, 2); acc += __shfl_xor(acc, 4);
    acc += __shfl_xor(acc, 8); acc += __shfl_xor(acc, 16); acc += __shfl_xor(acc, 32);
    if (lane == 0) bias_tab[i * NHEADS + h] = 16.f / (1.f + __expf(-acc));
  }
}

// ---------------- combined bias: cb[w][h][n][m] = rpb + mask (fp32, x4 vectorized) ----------------
__global__ __launch_bounds__(256) void cbias_kernel(const int* __restrict__ rpi,
                                                    const float* __restrict__ bias_tab,
                                                    const float* __restrict__ mask,
                                                    float* __restrict__ cb) {
  int e4 = blockIdx.x * 256 + threadIdx.x;
  if (e4 >= NWIN * NHEADS * NTOK * NTOK / 4) return;
  int m0 = (e4 * 4) % NTOK;
  int t = (e4 * 4) / NTOK;
  int n = t % NTOK; t /= NTOK;
  int h = t % NHEADS;
  int w = t / NHEADS;
  int4 idx = *(const int4*)(rpi + n * NTOK + m0);
  float4 mk = *(const float4*)(mask + ((size_t)(w * NTOK + n)) * NTOK + m0);
  float4 r;
  r.x = bias_tab[idx.x * NHEADS + h] + mk.x;
  r.y = bias_tab[idx.y * NHEADS + h] + mk.y;
  r.z = bias_tab[idx.z * NHEADS + h] + mk.z;
  r.w = bias_tab[idx.w * NHEADS + h] + mk.w;
  *(float4*)(cb + (size_t)e4 * 4) = r;
}

// ---------------- fused QKV-projection + cosine attention per (window b, head-PAIR hp) ----------------
// R22 == R21 verbatim (proven 243us attn): 3x3 phase-1 wave grid, role-specialized
// phase 2, half-buffered swizzled staging, depth-2 prefetch, 2 heads/block.
__global__ __launch_bounds__(576) void attn_fused(
    const u16* __restrict__ xb, const u16* __restrict__ wb,
    const float* __restrict__ q_bias, const float* __restrict__ k_bias,
    const float* __restrict__ v_bias, const float* __restrict__ cb,
    const float* __restrict__ scalev, u16* __restrict__ ctx) {
  __shared__ u16 smem[22656];  // 45312 B
  u16* qn = smem;               // [144][40] (per-head phases 2+)
  u16* kn = smem + 5760;        // [144][40]
  u16* vT = smem + 11520;       // [32][168]
  u16* Pc = smem + 16896;       // [144][40] (phase 5, wave-private rows)
  u16* xs = smem;               // phase 1: [144][64] half-buffered x rows (18432 B)
  u16* wsm = smem + 9216;       // phase 1: [192][64] half-buffered W rows, 2 heads (24576 B)

  // w-grouped XCD decode: XCD x owns mask-windows {2x,2x+1}; cb set = 2.4MB < 4MB L2
  int bid = blockIdx.x;
  int xcd = bid & 7;
  int i = bid >> 3;          // 0..383
  int wsub = i / 192;        // 0..1
  int j = i - wsub * 192;    // 0..191
  int bI = j / 6;            // 0..31
  int hp = j - bI * 6;       // 0..5 head pair
  int w = xcd * 2 + wsub;
  int b = bI * NWIN + w;
  int h0 = hp * 2;

  int tid = threadIdx.x;
  int lane = tid & 63, wv = tid >> 6;   // wv 0..8
  int g = lane >> 4, c = lane & 15;
  int rbase = wv * 16;                  // phases 3-5 row ownership
  int wr3 = wv / 3, wc3 = wv % 3;       // phase-1/2 tile: rows wr3*48.., cols wc3*64..

  // ---- phase 1: QKV for BOTH heads, K chunked by 32, prefetch depth 2, 3x3 wave grid ----
  f32x4 acc[3][4];
#pragma unroll
  for (int mi = 0; mi < 3; ++mi)
#pragma unroll
    for (int ni = 0; ni < 4; ++ni) acc[mi][ni] = (f32x4){0.f, 0.f, 0.f, 0.f};

  int r4 = tid >> 2, b4 = tid & 3;   // x/W0 row r4, 16B content chunk b4
  bool hasW1 = tid < 192;            // W rows 144..191 on threads 0..191
  int wr1 = 144 + r4;
  int wg0 = (r4 >> 6) * DIMC + (h0 + ((r4 >> 5) & 1)) * 32 + (r4 & 31);
  int wg1 = (wr1 >> 6) * DIMC + (h0 + ((wr1 >> 5) & 1)) * 32 + (wr1 & 31);
  const u16* xg = xb + ((size_t)b * NTOK + r4) * DIMC + b4 * 8;
  const u16* wgp0 = wb + (size_t)wg0 * DIMC + b4 * 8;
  const u16* wgp1 = wb + (size_t)wg1 * DIMC + b4 * 8;
  // half-buffer slots: content chunk (b4 + 4*parity), slot = chunk ^ (row&7)
  int xo0 = r4 * 64 + 8 * (b4 ^ (r4 & 7));
  int xo1 = r4 * 64 + 8 * ((b4 + 4) ^ (r4 & 7));
  int w1o0 = wr1 * 64 + 8 * (b4 ^ (wr1 & 7));
  int w1o1 = wr1 * 64 + 8 * ((b4 + 4) ^ (wr1 & 7));

  // named depth-2 buffers (A = even tiles, B = odd tiles)
  uint4 pxA, pw0A, pw1A, pxB, pw0B, pw1B;
  pxA = *(const uint4*)(xg);
  pw0A = *(const uint4*)(wgp0);
  if (hasW1) pw1A = *(const uint4*)(wgp1);
  pxB = *(const uint4*)(xg + 32);
  pw0B = *(const uint4*)(wgp0 + 32);
  if (hasW1) pw1B = *(const uint4*)(wgp1 + 32);

#pragma unroll
  for (int tt = 0; tt < 6; ++tt) {
    // ---- even sub-iter: tile t=2tt (half 0) ----
    *(uint4*)(xs + xo0) = pxA;
    *(uint4*)(wsm + xo0) = pw0A;
    if (hasW1) *(uint4*)(wsm + w1o0) = pw1A;
    __syncthreads();
    if (tt < 5) {  // issue loads for tile 2tt+2 (2 iterations of cover)
      int k0 = (2 * tt + 2) * 32;
      pxA = *(const uint4*)(xg + k0);
      pw0A = *(const uint4*)(wgp0 + k0);
      if (hasW1) pw1A = *(const uint4*)(wgp1 + k0);
    }
    {
      short8 ax[3];
#pragma unroll
      for (int mi = 0; mi < 3; ++mi) {
        int arow = wr3 * 48 + mi * 16 + c;
        ax[mi] = *(const short8*)(xs + arow * 64 + 8 * (g ^ (arow & 7)));
      }
#pragma unroll
      for (int ni = 0; ni < 4; ++ni) {
        int row = wc3 * 64 + ni * 16 + c;
        short8 bw = *(const short8*)(wsm + row * 64 + 8 * (g ^ (row & 7)));
#pragma unroll
        for (int mi = 0; mi < 3; ++mi) acc[mi][ni] = MFMA(ax[mi], bw, acc[mi][ni]);
      }
    }
    // ---- odd sub-iter: tile t=2tt+1 (half 1) ----
    *(uint4*)(xs + xo1) = pxB;
    *(uint4*)(wsm + xo1) = pw0B;
    if (hasW1) *(uint4*)(wsm + w1o1) = pw1B;
    __syncthreads();
    if (tt < 5) {  // issue loads for tile 2tt+3
      int k0 = (2 * tt + 3) * 32;
      pxB = *(const uint4*)(xg + k0);
      pw0B = *(const uint4*)(wgp0 + k0);
      if (hasW1) pw1B = *(const uint4*)(wgp1 + k0);
    }
    {
      short8 ax[3];
#pragma unroll
      for (int mi = 0; mi < 3; ++mi) {
        int arow = wr3 * 48 + mi * 16 + c;
        ax[mi] = *(const short8*)(xs + arow * 64 + 8 * ((g + 4) ^ (arow & 7)));
      }
#pragma unroll
      for (int ni = 0; ni < 4; ++ni) {
        int row = wc3 * 64 + ni * 16 + c;
        short8 bw = *(const short8*)(wsm + row * 64 + 8 * ((g + 4) ^ (row & 7)));
#pragma unroll
        for (int mi = 0; mi < 3; ++mi) acc[mi][ni] = MFMA(ax[mi], bw, acc[mi][ni]);
      }
    }
    // no trailing barrier: next sub-iter writes the other half
  }
  __syncthreads();  // phase-1 reads done; smem may be repurposed

  // ---- phases 2-5 per head (sequential, shared buffers) ----
#pragma unroll
  for (int hh = 0; hh < 2; ++hh) {
    int h = h0 + hh;
    if (hh) __syncthreads();  // head B waits for head A's LDS reads

    // phase 2 (role-specialized): wc3=0 -> qn, wc3=1 -> kn, wc3=2 -> vT.
    float sch = scalev[h];
    if (wc3 == 0) {
      float qb0 = q_bias[h * 32 + c], qb1 = q_bias[h * 32 + 16 + c];
#pragma unroll
      for (int mi = 0; mi < 3; ++mi) {
#pragma unroll
        for (int r = 0; r < 4; ++r) {
          int row = wr3 * 48 + mi * 16 + g * 4 + r;
          float q0 = acc[mi][hh * 2][r] + qb0, q1 = acc[mi][hh * 2 + 1][r] + qb1;
          float ssq = q0 * q0 + q1 * q1;
          ssq += __shfl_xor(ssq, 1); ssq += __shfl_xor(ssq, 2);
          ssq += __shfl_xor(ssq, 4); ssq += __shfl_xor(ssq, 8);
          float siq = sch / sqrtf(ssq);
          qn[row * 40 + c] = f2bf(q0 * siq);
          qn[row * 40 + 16 + c] = f2bf(q1 * siq);
        }
      }
    } else if (wc3 == 1) {
      float kb0 = k_bias[h * 32 + c], kb1 = k_bias[h * 32 + 16 + c];
#pragma unroll
      for (int mi = 0; mi < 3; ++mi) {
#pragma unroll
        for (int r = 0; r < 4; ++r) {
          int row = wr3 * 48 + mi * 16 + g * 4 + r;
          float k0v = acc[mi][hh * 2][r] + kb0, k1v = acc[mi][hh * 2 + 1][r] + kb1;
          float ssk = k0v * k0v + k1v * k1v;
          ssk += __shfl_xor(ssk, 1); ssk += __shfl_xor(ssk, 2);
          ssk += __shfl_xor(ssk, 4); ssk += __shfl_xor(ssk, 8);
          float sik = 1.f / sqrtf(ssk);
          kn[row * 40 + c] = f2bf(k0v * sik);
          kn[row * 40 + 16 + c] = f2bf(k1v * sik);
        }
      }
    } else {
      float vb0 = v_bias[h * 32 + c], vb1 = v_bias[h * 32 + 16 + c];
#pragma unroll
      for (int mi = 0; mi < 3; ++mi) {
        float v0a[4], v1a[4];
#pragma unroll
        for (int r = 0; r < 4; ++r) {
          v0a[r] = acc[mi][hh * 2][r] + vb0;
          v1a[r] = acc[mi][hh * 2 + 1][r] + vb1;
        }
        int m0 = wr3 * 48 + mi * 16 + g * 4;
        u16* p0 = vT + c * 168 + m0;
        u16* p1 = vT + (16 + c) * 168 + m0;
        *(u32*)p0 = cvtpk(v0a[0], v0a[1]);
        *(u32*)(p0 + 2) = cvtpk(v0a[2], v0a[3]);
        *(u32*)p1 = cvtpk(v1a[0], v1a[1]);
        *(u32*)(p1 + 2) = cvtpk(v1a[2], v1a[3]);
      }
    }
    if (hh == 0 && tid < 32) {  // zero vT m-pad (144..167) once
      uint4 z4 = {0u, 0u, 0u, 0u};
      *(uint4*)(vT + tid * 168 + 144) = z4;
      *(uint4*)(vT + tid * 168 + 152) = z4;
      *(uint4*)(vT + tid * 168 + 160) = z4;
    }
    __syncthreads();

    // phase 3: S = qn . kn^T
    short8 aq = *(const short8*)(qn + (rbase + c) * 40 + g * 8);
    f32x4 S[9];
#pragma unroll
    for (int mt = 0; mt < 9; ++mt) {
      short8 bk = *(const short8*)(kn + (mt * 16 + c) * 40 + g * 8);
      f32x4 z = (f32x4){0.f, 0.f, 0.f, 0.f};
      S[mt] = MFMA(aq, bk, z);
    }

    // phase 4: + (rpb + mask), row softmax (folded 1/sum into P)
    const float* cbh = cb + (((size_t)w * NHEADS + h) * NTOK) * NTOK;
#pragma unroll
    for (int r = 0; r < 4; ++r) {
      int row = rbase + g * 4 + r;
      const float* crow = cbh + (size_t)row * NTOK + c;
      float sv[9];
      float mx = -1e30f;
#pragma unroll
      for (int mt = 0; mt < 9; ++mt) {
        float s = S[mt][r] + crow[mt * 16];
        sv[mt] = s;
        mx = fmaxf(mx, s);
      }
      mx = fmaxf(mx, __shfl_xor(mx, 1)); mx = fmaxf(mx, __shfl_xor(mx, 2));
      mx = fmaxf(mx, __shfl_xor(mx, 4)); mx = fmaxf(mx, __shfl_xor(mx, 8));
      float sum = 0.f;
#pragma unroll
      for (int mt = 0; mt < 9; ++mt) {
        float p = __expf(sv[mt] - mx);
        sv[mt] = p;
        sum += p;
      }
      sum += __shfl_xor(sum, 1); sum += __shfl_xor(sum, 2);
      sum += __shfl_xor(sum, 4); sum += __shfl_xor(sum, 8);
      float rinv = 1.f / sum;
#pragma unroll
      for (int mt = 0; mt < 9; ++mt) S[mt][r] = sv[mt] * rinv;
    }

    // phase 5: PV via per-wave P bounce (wave-private Pc rows, no barriers)
    f32x4 po[2];
    po[0] = (f32x4){0.f, 0.f, 0.f, 0.f};
    po[1] = (f32x4){0.f, 0.f, 0.f, 0.f};
    for (int ck = 0; ck < 5; ++ck) {
#pragma unroll
      for (int mt2 = 0; mt2 < 2; ++mt2) {
        int MT = ck * 2 + mt2;
#pragma unroll
        for (int r = 0; r < 4; ++r) {
          int row = rbase + g * 4 + r;
          float p = (MT < 9) ? S[MT][r] : 0.f;
          Pc[row * 40 + mt2 * 16 + c] = f2bf(p);
        }
      }
      short8 pa = *(const short8*)(Pc + (rbase + c) * 40 + g * 8);
#pragma unroll
      for (int dt = 0; dt < 2; ++dt) {
        short8 vb = *(const short8*)(vT + (dt * 16 + c) * 168 + ck * 32 + g * 8);
        po[dt] = MFMA(pa, vb, po[dt]);
      }
    }

    // epilogue: ctx[b*144+n][h*32+d] bf16
#pragma unroll
    for (int dt = 0; dt < 2; ++dt)
#pragma unroll
      for (int r = 0; r < 4; ++r) {
        int n = rbase + g * 4 + r;
        ctx[((size_t)b * NTOK + n) * DIMC + h * 32 + dt * 16 + c] = f2bf(po[dt][r]);
      }
  }
}

// ---------------- output projection: (73728 x 384) @ (384 x 384)^T + bias, bf16 MFMA ----------------
// R22: XCD-grouped decode — the 3 N-blocks sharing an M-block's ctx rows land on the
// SAME XCD consecutively (xcd=bid&7; nblk=i%3; mblk=xcd+8*(i/3); bijective 8x216=1728)
// -> ctx tile is L2-hit for 2 of 3 reads (was 3x HBM fetch with round-robin).
__global__ __launch_bounds__(256) void proj_gemm(const u16* __restrict__ ctx,
                                                 const u16* __restrict__ pwb,
                                                 const float* __restrict__ proj_b,
                                                 float* __restrict__ out) {
  __shared__ u16 As[128 * 64];
  __shared__ u16 Bs[128 * 64];
  int bid = blockIdx.x;
  int xcd8 = bid & 7;
  int ii = bid >> 3;           // 0..215
  int nblk = ii % 3;
  int mblk = xcd8 + 8 * (ii / 3);  // 0..575
  size_t gm0 = (size_t)mblk * 128;
  int gn0 = nblk * 128;
  int tid = threadIdx.x, lane = tid & 63, wid = tid >> 6;
  int wr = wid >> 1, wc = wid & 1, g = lane >> 4, c = lane & 15;
  f32x4 acc[4][4];
#pragma unroll
  for (int i = 0; i < 4; ++i)
#pragma unroll
    for (int j = 0; j < 4; ++j) acc[i][j] = (f32x4){0.f, 0.f, 0.f, 0.f};

  for (int t = 0; t < 6; ++t) {
    int k0 = t * 64;
#pragma unroll
    for (int p = 0; p < 4; ++p) {
      int row = p * 32 + (tid >> 3);
      int seg = (tid & 7) * 8;
      uint4 va = *(const uint4*)(ctx + (gm0 + row) * DIMC + k0 + seg);
      *(uint4*)(As + row * 64 + seg) = va;
      uint4 vb = *(const uint4*)(pwb + (size_t)(gn0 + row) * DIMC + k0 + seg);
      *(uint4*)(Bs + row * 64 + seg) = vb;
    }
    __syncthreads();
#pragma unroll
    for (int kk = 0; kk < 64; kk += 32) {
      short8 a[4], bfr[4];
#pragma unroll
      for (int mi = 0; mi < 4; ++mi)
        a[mi] = *(const short8*)(As + (wr * 64 + mi * 16 + c) * 64 + kk + g * 8);
#pragma unroll
      for (int ni = 0; ni < 4; ++ni)
        bfr[ni] = *(const short8*)(Bs + (wc * 64 + ni * 16 + c) * 64 + kk + g * 8);
#pragma unroll
      for (int mi = 0; mi < 4; ++mi)
#pragma unroll
        for (int ni = 0; ni < 4; ++ni)
          acc[mi][ni] = MFMA(a[mi], bfr[ni], acc[mi][ni]);
    }
    __syncthreads();
  }
#pragma unroll
  for (int mi = 0; mi < 4; ++mi)
#pragma unroll
    for (int ni = 0; ni < 4; ++ni) {
      int gcol = gn0 + wc * 64 + ni * 16 + c;
      float bv = proj_b[gcol];
#pragma unroll
      for (int r = 0; r < 4; ++r) {
        size_t grow = gm0 + wr * 64 + mi * 16 + g * 4 + r;
        out[grow * DIMC + gcol] = acc[mi][ni][r] + bv;
      }
    }
}

extern "C" void kernel_launch(void* const* d_in, const int* in_sizes, int n_in,
                              void* d_out, int out_size, void* d_ws, size_t ws_size,
                              hipStream_t stream) {
  const float* x = (const float*)d_in[0];
  const float* rct = (const float*)d_in[1];
  const int* rpi = (const int*)d_in[2];
  const float* mask = (const float*)d_in[3];
  const float* qkv_w = (const float*)d_in[4];
  const float* q_bias = (const float*)d_in[5];
  const float* k_bias = (const float*)d_in[6];
  const float* v_bias = (const float*)d_in[7];
  const float* logit_scale = (const float*)d_in[8];
  const float* cpb_w1 = (const float*)d_in[9];
  const float* cpb_b1 = (const float*)d_in[10];
  const float* cpb_w2 = (const float*)d_in[11];
  const float* proj_w = (const float*)d_in[12];
  const float* proj_b = (const float*)d_in[13];
  float* out = (float*)d_out;

  char* ws = (char*)d_ws;
  size_t off = 0;
  auto alloc = [&](size_t bytes) {
    void* p = ws + off;
    off = (off + bytes + 255) & ~(size_t)255;
    return p;
  };
  const size_t NX = (size_t)BWIN * NTOK * DIMC;  // 28311552
  u16* xb = (u16*)alloc(NX * 2);
  u16* wqb = (u16*)alloc((size_t)3 * DIMC * DIMC * 2);
  u16* pwb = (u16*)alloc((size_t)DIMC * DIMC * 2);
  u16* ctx = (u16*)alloc(NX * 2);
  float* cbv = (float*)alloc((size_t)NWIN * NHEADS * NTOK * NTOK * 4);
  float* bias_tab = (float*)alloc((size_t)TABLEN * NHEADS * 4);
  float* scalev = (float*)alloc(64 * 4);

  cvt_bf16<<<(int)(NX / 8 + 255) / 256, 256, 0, stream>>>(x, xb, (int)(NX / 8));
  cvt_bf16<<<(3 * DIMC * DIMC / 8 + 255) / 256, 256, 0, stream>>>(qkv_w, wqb, 3 * DIMC * DIMC / 8);
  cvt_bf16<<<(DIMC * DIMC / 8 + 255) / 256, 256, 0, stream>>>(proj_w, pwb, DIMC * DIMC / 8);
  cpb_kernel<<<TABLEN, 256, 0, stream>>>(
      rct, cpb_w1, cpb_b1, cpb_w2, logit_scale, bias_tab, scalev);
  cbias_kernel<<<(NWIN * NHEADS * NTOK * NTOK / 4 + 255) / 256, 256, 0, stream>>>(
      rpi, bias_tab, mask, cbv);
  attn_fused<<<BWIN * 6, 576, 0, stream>>>(
      xb, wqb, q_bias, k_bias, v_bias, cbv, scalev, ctx);
  proj_gemm<<<(BWIN * NTOK / 128) * 3, 256, 0, stream>>>(ctx, pwb, proj_b, out);
}